// Round 6
// baseline (2160.145 us; speedup 1.0000x reference)
//
#include <hip/hip_runtime.h>
#include <hip/hip_bf16.h>

#define EPSF 1e-5f

typedef unsigned short u16;
typedef __attribute__((ext_vector_type(8))) short short8v;   // 8 bf16 bits (4 VGPRs)
typedef __attribute__((ext_vector_type(4))) float f32x4;

// ---------------------------------------------------------------------------
// Module-scope scratch. 84M floats = 336 MB, lifetime-aliased.
// Map (float offsets):
//   [       0,15360000) nh_hi  (bf16 [80000][384]: ch0-127 radar->enhanced, 128-383 image)
//   [15360000,30720000) nh_lo  (read by comb-proj; conv+gate read HI only)
//   [30720000,51200000) seq_comb fp32 [80000][256] -> hbuf (bf16 [80000][512]) after out-proj
//   [51200000,61440000) score/idx -> qh -> xbuf (fp32 80000x128)
//   [61440000,71680000) kvh fp32 [40000][256] -> gatepre fp32 [80000][128] (after attn)
//   [71680000,81920000) G: hscore fp32 [80000][128] -> kvn/qn/o/xn split-bf16 -> delta fp32
//   [81920000,82313216) WSEG: split weights (786432 u16 = 393216 floats)
//   [82330000,83657104) conv wgt hi/lo (2x1327104 u16)
//   [83900000,83900128) bias_pad (128 f, padded score_b1)
// d_out written ONLY by conv + bn_relu. d_ws unused. d_in never written.
// R4 lesson: simultaneous same-line misses from different XCDs don't merge —
// keep B-sharing tiles temporally separated (p-major gemm grid, hw-major conv).
// ---------------------------------------------------------------------------
__device__ float g_arena[84000000];
__device__ float g_stats[768];

// ---------------------------------------------------------------------------
// helpers
// ---------------------------------------------------------------------------
__device__ __forceinline__ float wave_sum(float v) {
#pragma unroll
    for (int o = 32; o > 0; o >>= 1) v += __shfl_down(v, o, 64);
    return v;
}

// split fp32 -> bf16 hi + bf16 lo (lo = bf16(x - fp32(hi))); residual ~2^-17 rel
__device__ __forceinline__ void bf_split(float v, u16& h, u16& l) {
    __hip_bfloat16 bh = __float2bfloat16(v);
    float hv = __bfloat162float(bh);
    __hip_bfloat16 bl = __float2bfloat16(v - hv);
    h = *reinterpret_cast<u16*>(&bh);
    l = *reinterpret_cast<u16*>(&bl);
}

__device__ __forceinline__ void store_split4(u16* ph, u16* pl, float4 v) {
    u16 h0, l0, h1, l1, h2, l2, h3, l3;
    bf_split(v.x, h0, l0); bf_split(v.y, h1, l1);
    bf_split(v.z, h2, l2); bf_split(v.w, h3, l3);
    *(ushort4*)ph = make_ushort4(h0, h1, h2, h3);
    *(ushort4*)pl = make_ushort4(l0, l1, l2, l3);
}

// ---------------------------------------------------------------------------
// split_weights: all gemm weights -> WSEG split bf16 (hi|lo per segment).
//   inproj   0      49152  | outproj 98304 16384 | ffn1 131072 65536
//   ffn2     262144 65536  | delta  393216 16384 | gate 425984 49152
//   comb     524288 98304  (zero-padded [256][384])
//   score1   720896 32768  (zero-padded [128][256], rows 64-127 = 0)
// plus bias_pad[128] = score_b1 padded. 393344 threads -> grid 1537 x 256.
// ---------------------------------------------------------------------------
__global__ __launch_bounds__(256) void split_weights_kernel(
    const float* __restrict__ w_inproj, const float* __restrict__ w_outproj,
    const float* __restrict__ w_ffn1, const float* __restrict__ w_ffn2,
    const float* __restrict__ w_delta, const float* __restrict__ w_gate,
    const float* __restrict__ w_img, const float* __restrict__ w_rad,
    const float* __restrict__ w_sc1, const float* __restrict__ b_sc1,
    u16* __restrict__ wseg, float* __restrict__ bias_pad)
{
    int i = blockIdx.x * 256 + threadIdx.x;
    if (i >= 393344) return;
    if (i >= 393216) {                       // bias_pad
        int l = i - 393216;
        bias_pad[l] = (l < 64) ? b_sc1[l] : 0.f;
        return;
    }
    float v; int base, numel, local;
    if (i < 49152)       { local = i;          base = 0;      numel = 49152; v = w_inproj[local]; }
    else if (i < 65536)  { local = i - 49152;  base = 98304;  numel = 16384; v = w_outproj[local]; }
    else if (i < 131072) { local = i - 65536;  base = 131072; numel = 65536; v = w_ffn1[local]; }
    else if (i < 196608) { local = i - 131072; base = 262144; numel = 65536; v = w_ffn2[local]; }
    else if (i < 212992) { local = i - 196608; base = 393216; numel = 16384; v = w_delta[local]; }
    else if (i < 262144) { local = i - 212992; base = 425984; numel = 49152; v = w_gate[local]; }
    else if (i < 360448) {
        local = i - 262144; base = 524288; numel = 98304;
        int oc = local / 384, c = local - oc * 384;
        if (oc < 128) v = (c < 128) ? w_rad[oc * 128 + c] : 0.f;
        else          v = (c >= 128) ? w_img[(oc - 128) * 256 + (c - 128)] : 0.f;
    } else {
        local = i - 360448; base = 720896; numel = 32768;
        int oc = local / 256, c = local - oc * 256;
        v = (oc < 64) ? w_sc1[oc * 256 + c] : 0.f;
    }
    u16 hh, ll;
    bf_split(v, hh, ll);
    wseg[base + local] = hh;
    wseg[base + numel + local] = ll;
}

// ---------------------------------------------------------------------------
// mfma_gemm: out[p][ocb+oc] = sum_k B[p][k] * W[ocb+oc][k]  (+bias,+resid,relu)
// Grid: (ceil(P/128), Nout/128) — p-tiles FASTEST (R4 lesson: B re-reads must
// be temporally separated, not simultaneous-cross-XCD).
// BMODE: 0 = split bf16 planes; 1 = single bf16; 2 = fp32 split-on-the-fly
// OMODE: 0 = fp32 out; 1 = bf16 out.  resid has row stride rstride.
// ---------------------------------------------------------------------------
template <int BMODE, int OMODE, bool RELU>
__global__ __launch_bounds__(256, 2) void mfma_gemm_kernel(
    const u16* __restrict__ Ah, const u16* __restrict__ Al,
    const u16* __restrict__ bh, const u16* __restrict__ bl,
    const float* __restrict__ bf, int bstride,
    const float* __restrict__ bias, const float* __restrict__ resid, int rstride,
    float* __restrict__ outf, u16* __restrict__ outh,
    int K, int Nout, int P)
{
    __shared__ alignas(16) u16 sAh[8192], sAl[8192], sBh[8192], sBl[8192];

    const int tid  = threadIdx.x;
    const int lane = tid & 63;
    const int wid  = tid >> 6;
    const int wrm  = wid >> 1;
    const int wcn  = wid & 1;
    const int p0   = blockIdx.x * 128;
    const int ocb  = blockIdx.y * 128;

    const int r0  = tid >> 3;
    const int cl  = tid & 7;
    const int swz = cl ^ (r0 & 7);

    f32x4 acc[4][4];
#pragma unroll
    for (int i = 0; i < 4; ++i)
#pragma unroll
        for (int j = 0; j < 4; ++j) acc[i][j] = (f32x4){0.f, 0.f, 0.f, 0.f};

    const int fr = lane & 15;
    const int fc = lane >> 4;

    for (int kk = 0; kk < K; kk += 64) {
        __syncthreads();
#pragma unroll
        for (int k = 0; k < 4; ++k) {
            int row = r0 + k * 32;
            int di = row * 64 + swz * 8;
            size_t ga = (size_t)(ocb + row) * K + kk + cl * 8;
            *(short8v*)&sAh[di] = *(const short8v*)&Ah[ga];
            *(short8v*)&sAl[di] = *(const short8v*)&Al[ga];
            int p = p0 + row;
            if (BMODE == 0) {
                if (p < P) {
                    size_t gb = (size_t)p * bstride + kk + cl * 8;
                    *(short8v*)&sBh[di] = *(const short8v*)&bh[gb];
                    *(short8v*)&sBl[di] = *(const short8v*)&bl[gb];
                } else {
                    short8v z = {0,0,0,0,0,0,0,0};
                    *(short8v*)&sBh[di] = z;
                    *(short8v*)&sBl[di] = z;
                }
            } else if (BMODE == 1) {
                if (p < P) {
                    size_t gb = (size_t)p * bstride + kk + cl * 8;
                    *(short8v*)&sBh[di] = *(const short8v*)&bh[gb];
                } else {
                    short8v z = {0,0,0,0,0,0,0,0};
                    *(short8v*)&sBh[di] = z;
                }
            } else {
                short8v vh8 = {0,0,0,0,0,0,0,0}, vl8 = {0,0,0,0,0,0,0,0};
                if (p < P) {
                    const float* src = bf + (size_t)p * bstride + kk + cl * 8;
                    float4 f0 = *(const float4*)(src);
                    float4 f1 = *(const float4*)(src + 4);
                    float fv[8] = {f0.x, f0.y, f0.z, f0.w, f1.x, f1.y, f1.z, f1.w};
#pragma unroll
                    for (int j = 0; j < 8; ++j) {
                        u16 hh, ll;
                        bf_split(fv[j], hh, ll);
                        vh8[j] = (short)hh;
                        vl8[j] = (short)ll;
                    }
                }
                *(short8v*)&sBh[di] = vh8;
                *(short8v*)&sBl[di] = vl8;
            }
        }
        __syncthreads();
#pragma unroll
        for (int h = 0; h < 2; ++h) {
            const int kc = h * 4 + fc;
            short8v bhf[4], blf[4];
#pragma unroll
            for (int nn = 0; nn < 4; ++nn) {
                int row = wcn * 64 + nn * 16 + fr;
                int idx = row * 64 + ((kc ^ (row & 7)) << 3);
                bhf[nn] = *(const short8v*)&sBh[idx];
                if (BMODE != 1) blf[nn] = *(const short8v*)&sBl[idx];
            }
#pragma unroll
            for (int mm = 0; mm < 4; ++mm) {
                int row = wrm * 64 + mm * 16 + fr;
                int idx = row * 64 + ((kc ^ (row & 7)) << 3);
                short8v ahf = *(const short8v*)&sAh[idx];
                short8v alf = *(const short8v*)&sAl[idx];
#pragma unroll
                for (int nn = 0; nn < 4; ++nn)
                    acc[mm][nn] = __builtin_amdgcn_mfma_f32_16x16x32_bf16(
                        ahf, bhf[nn], acc[mm][nn], 0, 0, 0);
                if (BMODE != 1) {
#pragma unroll
                    for (int nn = 0; nn < 4; ++nn)
                        acc[mm][nn] = __builtin_amdgcn_mfma_f32_16x16x32_bf16(
                            ahf, blf[nn], acc[mm][nn], 0, 0, 0);
                }
#pragma unroll
                for (int nn = 0; nn < 4; ++nn)
                    acc[mm][nn] = __builtin_amdgcn_mfma_f32_16x16x32_bf16(
                        alf, bhf[nn], acc[mm][nn], 0, 0, 0);
            }
        }
    }

    // epilogue: D[row=oc][col=pos] -> out[p][oc], 4 regs = 4 consecutive oc
#pragma unroll
    for (int mm = 0; mm < 4; ++mm) {
        int base = ocb + wrm * 64 + mm * 16 + fc * 4;
        float4 bv = {0.f, 0.f, 0.f, 0.f};
        if (bias) bv = *(const float4*)&bias[base];
#pragma unroll
        for (int nn = 0; nn < 4; ++nn) {
            int p = p0 + wcn * 64 + nn * 16 + fr;
            if (p < P) {
                size_t row = (size_t)p * Nout + base;
                float4 r;
                r.x = acc[mm][nn][0] + bv.x;
                r.y = acc[mm][nn][1] + bv.y;
                r.z = acc[mm][nn][2] + bv.z;
                r.w = acc[mm][nn][3] + bv.w;
                if (resid) {
                    float4 rr = *(const float4*)&resid[(size_t)p * rstride + base - ocb];
                    r.x += rr.x; r.y += rr.y; r.z += rr.z; r.w += rr.w;
                }
                if (RELU) {
                    r.x = fmaxf(r.x, 0.f); r.y = fmaxf(r.y, 0.f);
                    r.z = fmaxf(r.z, 0.f); r.w = fmaxf(r.w, 0.f);
                }
                if (OMODE == 0) {
                    *(float4*)&outf[row] = r;
                } else {
                    __hip_bfloat16 b0 = __float2bfloat16(r.x);
                    __hip_bfloat16 b1 = __float2bfloat16(r.y);
                    __hip_bfloat16 b2 = __float2bfloat16(r.z);
                    __hip_bfloat16 b3 = __float2bfloat16(r.w);
                    *(ushort4*)&outh[row] = make_ushort4(
                        *reinterpret_cast<u16*>(&b0), *reinterpret_cast<u16*>(&b1),
                        *reinterpret_cast<u16*>(&b2), *reinterpret_cast<u16*>(&b3));
                }
            }
        }
    }
}

// ---------------------------------------------------------------------------
// score_reduce: score[p] = h[p][0:64] . w2 + b2  (h from MFMA score-gemm)
// one wave per row, 4 rows/block, grid 20000
// ---------------------------------------------------------------------------
__global__ __launch_bounds__(256) void score_reduce_kernel(
    const float* __restrict__ h, const float* __restrict__ w2,
    const float* __restrict__ b2, float* __restrict__ score)
{
    int p = blockIdx.x * 4 + (threadIdx.x >> 6);
    int l = threadIdx.x & 63;
    float v = h[(size_t)p * 128 + l] * w2[l];
    v = wave_sum(v);
    if (l == 0) score[p] = v + b2[0];
}

// ---------------------------------------------------------------------------
// topk: exact stable rank selection (matches jax.lax.top_k tie-breaking)
// ---------------------------------------------------------------------------
__global__ __launch_bounds__(256) void topk_kernel(
    const float* __restrict__ score, int* __restrict__ idx)
{
    __shared__ float s[200];
    const int n = blockIdx.x;
    const int t = threadIdx.x;
    if (t < 200) s[t] = score[(size_t)n * 200 + t];
    __syncthreads();
    if (t < 200) {
        float my = s[t];
        int cnt = 0;
        for (int j = 0; j < 200; j++) {
            float o = s[j];
            cnt += (o > my) || (o == my && j < t);
        }
        if (cnt < 100) idx[n * 100 + cnt] = t;
    }
}

// ---------------------------------------------------------------------------
// ln_gather: out[r][:] = LN(in[src_row][:]) * g + b  -> split bf16 planes
// ---------------------------------------------------------------------------
__global__ __launch_bounds__(256) void ln_gather_kernel(
    const float* __restrict__ in, int stride, const int* __restrict__ gidx,
    const float* __restrict__ g, const float* __restrict__ bb,
    u16* __restrict__ oh, u16* __restrict__ ol)
{
    __shared__ float red[4];
    const int tid = threadIdx.x;
    const int grp = tid >> 7;
    const int t = tid & 127;
    const int r = blockIdx.x * 2 + grp;

    size_t src_row;
    if (gidx) src_row = (size_t)(r / 100) * 200 + gidx[r];
    else      src_row = (size_t)r;

    float x = in[src_row * stride + t];
    float s = wave_sum(x);
    if ((tid & 63) == 0) red[tid >> 6] = s;
    __syncthreads();
    float m = (red[grp * 2] + red[grp * 2 + 1]) * 0.0078125f;
    float d = x - m;
    float s2 = wave_sum(d * d);
    __syncthreads();
    if ((tid & 63) == 0) red[tid >> 6] = s2;
    __syncthreads();
    float var = (red[grp * 2] + red[grp * 2 + 1]) * 0.0078125f;
    float y = d * rsqrtf(var + EPSF) * g[t] + bb[t];
    u16 hh, ll;
    bf_split(y, hh, ll);
    oh[(size_t)r * 128 + t] = hh;
    ol[(size_t)r * 128 + t] = ll;
}

// ---------------------------------------------------------------------------
// attention: block = (head h, row n); thread = one query w (<200)
// K/V interleaved in kvh [40000][256]; outputs split bf16 planes
// ---------------------------------------------------------------------------
__global__ __launch_bounds__(256) void attention_kernel(
    const float* __restrict__ qh, const float* __restrict__ kvh,
    u16* __restrict__ o_hi, u16* __restrict__ o_lo)
{
    __shared__ float sk[100][16];
    __shared__ float sv[100][16];
    const int h = blockIdx.x;
    const int n = blockIdx.y;
    const int tid = threadIdx.x;

    for (int e = tid; e < 1600; e += 256) {
        int kk = e >> 4, d = e & 15;
        size_t src = ((size_t)n * 100 + kk) * 256 + h * 16 + d;
        sk[kk][d] = kvh[src];
        sv[kk][d] = kvh[src + 128];
    }
    __syncthreads();

    if (tid < 200) {
        const float* qp = &qh[((size_t)n * 200 + tid) * 128 + h * 16];
        float4 q0 = *(const float4*)(qp + 0);
        float4 q1 = *(const float4*)(qp + 4);
        float4 q2 = *(const float4*)(qp + 8);
        float4 q3 = *(const float4*)(qp + 12);

        float m = -INFINITY, l = 0.f;
        float4 a0 = {0,0,0,0}, a1 = {0,0,0,0}, a2 = {0,0,0,0}, a3 = {0,0,0,0};

        for (int kk = 0; kk < 100; kk++) {
            const float4* kp = (const float4*)&sk[kk][0];
            float s = q0.x*kp[0].x + q0.y*kp[0].y + q0.z*kp[0].z + q0.w*kp[0].w
                    + q1.x*kp[1].x + q1.y*kp[1].y + q1.z*kp[1].z + q1.w*kp[1].w
                    + q2.x*kp[2].x + q2.y*kp[2].y + q2.z*kp[2].z + q2.w*kp[2].w
                    + q3.x*kp[3].x + q3.y*kp[3].y + q3.z*kp[3].z + q3.w*kp[3].w;
            s *= 0.25f;
            float nm = fmaxf(m, s);
            float corr = __expf(m - nm);
            float pe = __expf(s - nm);
            l = l * corr + pe;
            const float4* vp = (const float4*)&sv[kk][0];
            float4 v0 = vp[0], v1 = vp[1], v2 = vp[2], v3 = vp[3];
            a0.x = a0.x * corr + pe * v0.x; a0.y = a0.y * corr + pe * v0.y;
            a0.z = a0.z * corr + pe * v0.z; a0.w = a0.w * corr + pe * v0.w;
            a1.x = a1.x * corr + pe * v1.x; a1.y = a1.y * corr + pe * v1.y;
            a1.z = a1.z * corr + pe * v1.z; a1.w = a1.w * corr + pe * v1.w;
            a2.x = a2.x * corr + pe * v2.x; a2.y = a2.y * corr + pe * v2.y;
            a2.z = a2.z * corr + pe * v2.z; a2.w = a2.w * corr + pe * v2.w;
            a3.x = a3.x * corr + pe * v3.x; a3.y = a3.y * corr + pe * v3.y;
            a3.z = a3.z * corr + pe * v3.z; a3.w = a3.w * corr + pe * v3.w;
            m = nm;
        }
        float inv = 1.f / l;
        a0.x *= inv; a0.y *= inv; a0.z *= inv; a0.w *= inv;
        a1.x *= inv; a1.y *= inv; a1.z *= inv; a1.w *= inv;
        a2.x *= inv; a2.y *= inv; a2.z *= inv; a2.w *= inv;
        a3.x *= inv; a3.y *= inv; a3.z *= inv; a3.w *= inv;
        size_t ob = ((size_t)n * 200 + tid) * 128 + h * 16;
        store_split4(&o_hi[ob + 0],  &o_lo[ob + 0],  a0);
        store_split4(&o_hi[ob + 4],  &o_lo[ob + 4],  a1);
        store_split4(&o_hi[ob + 8],  &o_lo[ob + 8],  a2);
        store_split4(&o_hi[ob + 12], &o_lo[ob + 12], a3);
    }
}

// ---------------------------------------------------------------------------
// prep_weights: fuse_w [oc][ic][ky][kx] fp32 -> conv wgt hi/lo [oc][s][ic] bf16
// ---------------------------------------------------------------------------
__global__ __launch_bounds__(256) void prep_weights_kernel(
    const float* __restrict__ fw, u16* __restrict__ wh, u16* __restrict__ wl)
{
    int idx = blockIdx.x * 256 + threadIdx.x;   // < 384*384 = 147456
    int oc = idx / 384;
    int ic = idx - oc * 384;
    const float* src = fw + (size_t)idx * 9;
    u16* dh = wh + (size_t)oc * 3456 + ic;
    u16* dl = wl + (size_t)oc * 3456 + ic;
#pragma unroll
    for (int s = 0; s < 9; ++s) {
        u16 hh, ll;
        bf_split(src[s], hh, ll);
        dh[(size_t)s * 384] = hh;
        dl[(size_t)s * 384] = ll;
    }
}

// ---------------------------------------------------------------------------
// convert_nhwc: concat(radar[0:128], image[0:256]) NCHW fp32 -> NHWC bf16 split
// ---------------------------------------------------------------------------
__global__ __launch_bounds__(256) void convert_nhwc_kernel(
    const float* __restrict__ radar, const float* __restrict__ image,
    u16* __restrict__ oh, u16* __restrict__ ol)
{
    int p = blockIdx.x * 256 + threadIdx.x;
    if (p >= 80000) return;
    int cg = blockIdx.y;               // 0..5 -> channels [cg*64, cg*64+64)
    int b = p >= 40000 ? 1 : 0;
    int hw = p - b * 40000;
    u16* ph = oh + (size_t)p * 384 + cg * 64;
    u16* pl = ol + (size_t)p * 384 + cg * 64;
#pragma unroll 1
    for (int g = 0; g < 8; ++g) {
        short8v vh, vl;
#pragma unroll
        for (int j = 0; j < 8; ++j) {
            int c = cg * 64 + g * 8 + j;
            float v = (c < 128)
                ? radar[((size_t)(b * 128 + c)) * 40000 + hw]
                : image[((size_t)(b * 256 + (c - 128))) * 40000 + hw];
            u16 hh, ll;
            bf_split(v, hh, ll);
            vh[j] = (short)hh;
            vl[j] = (short)ll;
        }
        *(short8v*)&ph[g * 8] = vh;
        *(short8v*)&pl[g * 8] = vl;
    }
}

// ---------------------------------------------------------------------------
// enhance_fuse: nh[p][0:128] = bf16(radar + gamma*sigmoid(gatepre)*rmask*delta)
// HI plane only — nh_lo radar chunk is dead (conv + gate read hi only).
// ---------------------------------------------------------------------------
__global__ __launch_bounds__(256) void enhance_fuse_kernel(
    const float* __restrict__ delta, const float* __restrict__ gatepre,
    const float* __restrict__ radar, const float* __restrict__ gamma_p,
    u16* __restrict__ nh)
{
    __shared__ float srad[64][136];   // [pos][oc], padded
    const int tid = threadIdx.x;
    const int blk = blockIdx.x;        // 0..1249 (625 per b)
    const int b = blk >= 625 ? 1 : 0;
    const int hw0 = (blk - b * 625) * 64;
    const int p0 = b * 40000 + hw0;

#pragma unroll
    for (int i = 0; i < 32; ++i) {
        int e = tid + i * 256;         // 8192 elems
        int oc = e >> 6, pos = e & 63;
        srad[pos][oc] = radar[((size_t)(b * 128 + oc)) * 40000 + hw0 + pos];
    }
    __syncthreads();

    const float gmm = gamma_p[0];
    const int c4 = tid & 31;           // oc quad index
    const int rr = tid >> 5;           // 0..7
#pragma unroll
    for (int j = 0; j < 8; ++j) {
        int pos = j * 8 + rr;
        int p = p0 + pos;
        int hw = hw0 + pos;
        int hrow = hw / 200;
        float rm = fmaxf(0.3f, 1.0f - 0.7f * ((float)hrow * (1.0f / 199.0f)));
        float4 dv = *(const float4*)&delta[(size_t)p * 128 + c4 * 4];
        float4 gv = *(const float4*)&gatepre[(size_t)p * 128 + c4 * 4];
        float4 rv = *(const float4*)&srad[pos][c4 * 4];
        float rx = rv.x + gmm * (1.f / (1.f + __expf(-gv.x))) * rm * dv.x;
        float ry = rv.y + gmm * (1.f / (1.f + __expf(-gv.y))) * rm * dv.y;
        float rz = rv.z + gmm * (1.f / (1.f + __expf(-gv.z))) * rm * dv.z;
        float rw = rv.w + gmm * (1.f / (1.f + __expf(-gv.w))) * rm * dv.w;
        __hip_bfloat16 b0 = __float2bfloat16(rx);
        __hip_bfloat16 b1 = __float2bfloat16(ry);
        __hip_bfloat16 b2 = __float2bfloat16(rz);
        __hip_bfloat16 b3 = __float2bfloat16(rw);
        *(ushort4*)&nh[(size_t)p * 384 + c4 * 4] = make_ushort4(
            *reinterpret_cast<u16*>(&b0), *reinterpret_cast<u16*>(&b1),
            *reinterpret_cast<u16*>(&b2), *reinterpret_cast<u16*>(&b3));
    }
}

// ---------------------------------------------------------------------------
// conv_mfma: 3x3 SAME conv as 9 shifted GEMMs on matrix cores.
// R6: icb OUTER, shift INNER — consecutive shifts re-read overlapping rows
// within one icb window, so re-reads hit L2 (R5 had shift outer: by the time
// shift s+1 re-read the rows, 6 icb stages had evicted them -> 982 MB FETCH).
// Input = HI bf16 plane only (2 MFMA products). LDS 48 KB -> 3 blocks/CU.
// Grid (313,2,3) hw-major (R4 lesson).
// ---------------------------------------------------------------------------
__global__ __launch_bounds__(256, 3) void conv_mfma_kernel(
    const u16* __restrict__ nhwc_hi,
    const u16* __restrict__ wgt_hi,  const u16* __restrict__ wgt_lo,
    float* __restrict__ out)
{
    __shared__ alignas(16) u16 sAh[8192], sAl[8192], sBh[8192];  // 48 KB

    const int tid  = threadIdx.x;
    const int lane = tid & 63;
    const int wid  = tid >> 6;
    const int wrm  = wid >> 1;
    const int wcn  = wid & 1;
    const int hw0  = blockIdx.x * 128;
    const int b    = blockIdx.y;
    const int oc0  = blockIdx.z * 128;

    const int r0  = tid >> 3;
    const int cl  = tid & 7;
    const int swz = cl ^ (r0 & 7);

    const int y0 = hw0 / 200;
    const int x0 = hw0 - y0 * 200;

    f32x4 acc[4][4];
#pragma unroll
    for (int i = 0; i < 4; ++i)
#pragma unroll
        for (int j = 0; j < 4; ++j) acc[i][j] = (f32x4){0.f, 0.f, 0.f, 0.f};

    size_t abase[4];
#pragma unroll
    for (int k = 0; k < 4; ++k)
        abase[k] = (size_t)(oc0 + r0 + k * 32) * 3456 + cl * 8;

    const int fr = lane & 15;
    const int fc = lane >> 4;

    for (int icb = 0; icb < 6; ++icb) {
        const int ic0 = icb * 64;
        for (int s = 0; s < 9; ++s) {
            const int dy = s / 3 - 1;
            const int dx = s % 3 - 1;
            size_t bsrc[4];
            int bval[4];
#pragma unroll
            for (int k = 0; k < 4; ++k) {
                int row = r0 + k * 32;
                int hwo = hw0 + row;
                int xr  = x0 + row;
                int wrp = (xr >= 200) ? 1 : 0;
                int yy  = y0 + wrp + dy;
                int xx  = xr - wrp * 200 + dx;
                int v = (hwo < 40000) && ((unsigned)yy < 200u) && ((unsigned)xx < 200u);
                bval[k] = v;
                bsrc[k] = v ? ((size_t)(b * 40000 + yy * 200 + xx) * 384 + cl * 8 + ic0) : 0;
            }
            const size_t wofs = (size_t)s * 384 + ic0;

            __syncthreads();
#pragma unroll
            for (int k = 0; k < 4; ++k) {
                int di = (r0 + k * 32) * 64 + swz * 8;
                size_t ga = abase[k] + wofs;
                *(short8v*)&sAh[di] = *(const short8v*)&wgt_hi[ga];
                *(short8v*)&sAl[di] = *(const short8v*)&wgt_lo[ga];
                if (bval[k]) {
                    *(short8v*)&sBh[di] = *(const short8v*)&nhwc_hi[bsrc[k]];
                } else {
                    short8v z = {0, 0, 0, 0, 0, 0, 0, 0};
                    *(short8v*)&sBh[di] = z;
                }
            }
            __syncthreads();
#pragma unroll
            for (int h = 0; h < 2; ++h) {
                const int kc = h * 4 + fc;
                short8v bhf[4];
#pragma unroll
                for (int nn = 0; nn < 4; ++nn) {
                    int row = wcn * 64 + nn * 16 + fr;
                    int idx = row * 64 + ((kc ^ (row & 7)) << 3);
                    bhf[nn] = *(const short8v*)&sBh[idx];
                }
#pragma unroll
                for (int mm = 0; mm < 4; ++mm) {
                    int row = wrm * 64 + mm * 16 + fr;
                    int idx = row * 64 + ((kc ^ (row & 7)) << 3);
                    short8v ahf = *(const short8v*)&sAh[idx];
                    short8v alf = *(const short8v*)&sAl[idx];
#pragma unroll
                    for (int nn = 0; nn < 4; ++nn)
                        acc[mm][nn] = __builtin_amdgcn_mfma_f32_16x16x32_bf16(
                            ahf, bhf[nn], acc[mm][nn], 0, 0, 0);
#pragma unroll
                    for (int nn = 0; nn < 4; ++nn)
                        acc[mm][nn] = __builtin_amdgcn_mfma_f32_16x16x32_bf16(
                            alf, bhf[nn], acc[mm][nn], 0, 0, 0);
                }
            }
        }
    }

#pragma unroll
    for (int mm = 0; mm < 4; ++mm) {
        int oc = oc0 + wrm * 64 + mm * 16 + fc * 4;
#pragma unroll
        for (int nn = 0; nn < 4; ++nn) {
            int p = hw0 + wcn * 64 + nn * 16 + fr;
            if (p < 40000) {
                float* op = out + (size_t)(b * 384 + oc) * 40000 + p;
#pragma unroll
                for (int r = 0; r < 4; ++r)
                    op[(size_t)r * 40000] = acc[mm][nn][r];
            }
        }
    }
}

// ---------------------------------------------------------------------------
// zero_stats + conv_stats (4 hw-chunks per channel, atomic accumulate)
// ---------------------------------------------------------------------------
__global__ void zero_stats_kernel() {
    int i = blockIdx.x * 256 + threadIdx.x;
    if (i < 768) g_stats[i] = 0.f;
}

__global__ __launch_bounds__(256) void conv_stats_kernel(const float* __restrict__ out)
{
    const int c = blockIdx.x;           // 0..383
    const int chunk = blockIdx.y;       // 0..3
    float s1 = 0.f, s2 = 0.f;
#pragma unroll
    for (int b = 0; b < 2; ++b) {
        const float4* pp = (const float4*)(out + (size_t)(b * 384 + c) * 40000)
                         + (size_t)chunk * 2500;
        for (int i = threadIdx.x; i < 2500; i += 256) {
            float4 v = pp[i];
            s1 += v.x + v.y + v.z + v.w;
            s2 += v.x * v.x + v.y * v.y + v.z * v.z + v.w * v.w;
        }
    }
    s1 = wave_sum(s1);
    s2 = wave_sum(s2);
    __shared__ float r1[4], r2[4];
    if ((threadIdx.x & 63) == 0) {
        r1[threadIdx.x >> 6] = s1;
        r2[threadIdx.x >> 6] = s2;
    }
    __syncthreads();
    if (threadIdx.x == 0) {
        atomicAdd(&g_stats[c * 2],     r1[0] + r1[1] + r1[2] + r1[3]);
        atomicAdd(&g_stats[c * 2 + 1], r2[0] + r2[1] + r2[2] + r2[3]);
    }
}

// ---------------------------------------------------------------------------
// bn_relu: in-place on d_out
// ---------------------------------------------------------------------------
__global__ __launch_bounds__(256) void bn_relu_kernel(
    float* __restrict__ out, const float* __restrict__ g,
    const float* __restrict__ bb)
{
    int i = blockIdx.x * 256 + threadIdx.x;   // float4 index < 7,680,000
    int flat = i * 4;
    int oc = (flat / 40000) % 384;
    float m = g_stats[oc * 2] * (1.f / 80000.f);
    float v = g_stats[oc * 2 + 1] * (1.f / 80000.f) - m * m;
    float inv = rsqrtf(v + EPSF);
    float sc = g[oc] * inv;
    float sh = bb[oc] - m * sc;
    float4 c = ((float4*)out)[i];
    c.x = fmaxf(c.x * sc + sh, 0.f);
    c.y = fmaxf(c.y * sc + sh, 0.f);
    c.z = fmaxf(c.z * sc + sh, 0.f);
    c.w = fmaxf(c.w * sc + sh, 0.f);
    ((float4*)out)[i] = c;
}

// ---------------------------------------------------------------------------
// launch
// ---------------------------------------------------------------------------
extern "C" void kernel_launch(void* const* d_in, const int* in_sizes, int n_in,
                              void* d_out, int out_size, void* d_ws, size_t ws_size,
                              hipStream_t stream)
{
    (void)in_sizes; (void)n_in; (void)out_size; (void)d_ws; (void)ws_size;

    const float* radar      = (const float*)d_in[0];
    const float* image      = (const float*)d_in[1];
    const float* img_proj_w = (const float*)d_in[2];
    const float* rad_proj_w = (const float*)d_in[3];
    const float* in_proj_w  = (const float*)d_in[4];
    const float* in_proj_b  = (const float*)d_in[5];
    const float* out_proj_w = (const float*)d_in[6];
    const float* out_proj_b = (const float*)d_in[7];
    const float* ln1q_g     = (const float*)d_in[8];
    const float* ln1q_b     = (const float*)d_in[9];
    const float* ln1kv_g    = (const float*)d_in[10];
    const float* ln1kv_b    = (const float*)d_in[11];
    const float* ln2_g      = (const float*)d_in[12];
    const float* ln2_b      = (const float*)d_in[13];
    const float* ffn_w1     = (const float*)d_in[14];
    const float* ffn_b1     = (const float*)d_in[15];
    const float* ffn_w2     = (const float*)d_in[16];
    const float* ffn_b2     = (const float*)d_in[17];
    const float* score_w1   = (const float*)d_in[18];
    const float* score_b1   = (const float*)d_in[19];
    const float* score_w2   = (const float*)d_in[20];
    const float* score_b2   = (const float*)d_in[21];
    const float* rad_delta_w= (const float*)d_in[22];
    const float* gamma      = (const float*)d_in[23];
    const float* gate_w     = (const float*)d_in[24];
    const float* gate_b     = (const float*)d_in[25];
    const float* fuse_w     = (const float*)d_in[26];
    const float* bn_g       = (const float*)d_in[27];
    const float* bn_b       = (const float*)d_in[28];

    float* arena = nullptr;
    hipGetSymbolAddress((void**)&arena, HIP_SYMBOL(g_arena));

    // --- arena regions (see map above) ---
    u16*   nh_hi    = (u16*)arena;                      // [80000][384] hi
    u16*   nh_lo    = (u16*)(arena + 15360000);         // [80000][384] lo
    float* seq_comb = arena + 30720000;                 // [80000][256] fp32
    float* score    = arena + 51200000;                 // 80000 f
    int*   idx      = (int*)(arena + 51280000);         // 40000 int
    float* qh       = arena + 51200000;                 // overlays score/idx
    float* xbuf     = arena + 51200000;                 // overlays qh
    float* kvh      = arena + 61440000;                 // [40000][256] fp32
    float* gatepre  = arena + 61440000;                 // [80000][128] over kvh (after attn)
    float* hscore   = arena + 71680000;                 // [80000][128] fp32 (score MLP hidden)
    u16*   gbase    = (u16*)(arena + 71680000);         // split-plane region G (over dead hscore)
    u16*   kvn_hi   = gbase,            *kvn_lo = gbase + 5120000;   // [40000][128]
    u16*   qn_hi    = gbase,            *qn_lo  = gbase + 10240000;  // [80000][128]
    u16*   o_hi     = gbase,            *o_lo   = gbase + 10240000;  // [80000][128]
    u16*   xn_hi    = gbase,            *xn_lo  = gbase + 10240000;  // [80000][128]
    float* delta    = arena + 71680000;                 // [80000][128] over G
    u16*   hbuf     = (u16*)(arena + 30720000);         // [80000][512] bf16 over seq_comb
    u16*   wseg     = (u16*)(arena + 81920000);         // 786432 u16 -> ends 82313216 f
    u16*   cwgt_hi  = (u16*)(arena + 82330000);         // conv wgt
    u16*   cwgt_lo  = cwgt_hi + 1327104;                // ends 83657104 f
    float* bias_pad = arena + 83900000;                 // 128 f (padded score_b1)

    // split-weight sub-pointers (u16 offsets within wseg)
    const u16* w_q_hi    = wseg + 0,      *w_q_lo    = wseg + 49152;          // in_proj rows 0-127
    const u16* w_kv_hi   = wseg + 16384,  *w_kv_lo   = wseg + 49152 + 16384;  // rows 128-383 (256)
    const u16* w_out_hi  = wseg + 98304,  *w_out_lo  = wseg + 114688;
    const u16* w_ffn1_hi = wseg + 131072, *w_ffn1_lo = wseg + 196608;
    const u16* w_ffn2_hi = wseg + 262144, *w_ffn2_lo = wseg + 327680;
    const u16* w_dlt_hi  = wseg + 393216, *w_dlt_lo  = wseg + 409600;
    const u16* w_gate_hi = wseg + 425984, *w_gate_lo = wseg + 475136;
    const u16* w_comb_hi = wseg + 524288, *w_comb_lo = wseg + 622592;         // [256][384] padded
    const u16* w_sc1_hi  = wseg + 720896, *w_sc1_lo  = wseg + 753664;         // [128][256] padded

    const dim3 blk(256);

    // prep: weight splits + NHWC conversion of (radar|image)
    split_weights_kernel<<<dim3(1537), blk, 0, stream>>>(
        in_proj_w, out_proj_w, ffn_w1, ffn_w2, rad_delta_w, gate_w,
        img_proj_w, rad_proj_w, score_w1, score_b1, wseg, bias_pad);
    prep_weights_kernel<<<dim3(576), blk, 0, stream>>>(fuse_w, cwgt_hi, cwgt_lo);
    convert_nhwc_kernel<<<dim3(313, 6), blk, 0, stream>>>(radar, image, nh_hi, nh_lo);

    // combined projection: seq_comb[p][0:128]=rad, [128:256]=img
    mfma_gemm_kernel<0, 0, false><<<dim3(625, 2), blk, 0, stream>>>(
        w_comb_hi, w_comb_lo, nh_hi, nh_lo, nullptr, 384,
        nullptr, nullptr, 0, seq_comb, nullptr, 384, 256, 80000);

    // scoring MLP (MFMA, padded W1/bias) -> hscore; reduce with w2; top-k
    mfma_gemm_kernel<2, 0, true><<<dim3(625, 1), blk, 0, stream>>>(
        w_sc1_hi, w_sc1_lo, nullptr, nullptr, seq_comb, 256,
        bias_pad, nullptr, 0, hscore, nullptr, 256, 128, 80000);
    score_reduce_kernel<<<dim3(20000), blk, 0, stream>>>(
        hscore, score_w2, score_b2, score);
    topk_kernel<<<dim3(400), blk, 0, stream>>>(score, idx);

    // gathered LN(kv) -> kvn planes (over dead hscore); merged K+V projection
    ln_gather_kernel<<<dim3(20000), blk, 0, stream>>>(
        seq_comb + 128, 256, idx, ln1kv_g, ln1kv_b, kvn_hi, kvn_lo);
    mfma_gemm_kernel<0, 0, false><<<dim3(313, 2), blk, 0, stream>>>(
        w_kv_hi, w_kv_lo, kvn_hi, kvn_lo, nullptr, 128,
        in_proj_b + 128, nullptr, 0, kvh, nullptr, 128, 256, 40000);

    // LN(q) -> qn planes (over dead kvn), Q projection -> qh (over dead score/idx)
    ln_gather_kernel<<<dim3(40000), blk, 0, stream>>>(
        seq_comb, 256, nullptr, ln1q_g, ln1q_b, qn_hi, qn_lo);
    mfma_gemm_kernel<0, 0, false><<<dim3(625, 1), blk, 0, stream>>>(
        w_q_hi, w_q_lo, qn_hi, qn_lo, nullptr, 128,
        in_proj_b, nullptr, 0, qh, nullptr, 128, 128, 80000);

    // attention -> o planes (over dead qn)
    attention_kernel<<<dim3(8, 400), blk, 0, stream>>>(qh, kvh, o_hi, o_lo);

    // out-proj + residual (rad part of seq_comb, rstride 256) -> xbuf
    mfma_gemm_kernel<0, 0, false><<<dim3(625, 1), blk, 0, stream>>>(
        w_out_hi, w_out_lo, o_hi, o_lo, nullptr, 128,
        out_proj_b, seq_comb, 256, xbuf, nullptr, 128, 128, 80000);

    // FFN: ln2 -> xn planes (over dead o); FFN1 -> hbuf bf16 (over dead seq_comb);
    // FFN2 -> xbuf in place
    ln_gather_kernel<<<dim3(40000), blk, 0, stream>>>(
        xbuf, 128, nullptr, ln2_g, ln2_b, xn_hi, xn_lo);
    mfma_gemm_kernel<0, 1, true><<<dim3(625, 4), blk, 0, stream>>>(
        w_ffn1_hi, w_ffn1_lo, xn_hi, xn_lo, nullptr, 128,
        ffn_b1, nullptr, 0, nullptr, hbuf, 128, 512, 80000);
    mfma_gemm_kernel<1, 0, false><<<dim3(625, 1), blk, 0, stream>>>(
        w_ffn2_hi, w_ffn2_lo, hbuf, nullptr, nullptr, 512,
        ffn_b2, xbuf, 128, xbuf, nullptr, 512, 128, 80000);

    // enhance: delta gemm (fp32 B, over dead xn) + gate gemm (hi-only B, over
    // dead kvh) + fused sigmoid/rmask/residual writing nh radar channels
    mfma_gemm_kernel<2, 0, false><<<dim3(625, 1), blk, 0, stream>>>(
        w_dlt_hi, w_dlt_lo, nullptr, nullptr, xbuf, 128,
        nullptr, nullptr, 0, delta, nullptr, 128, 128, 80000);
    mfma_gemm_kernel<1, 0, false><<<dim3(625, 1), blk, 0, stream>>>(
        w_gate_hi, w_gate_lo, nh_hi, nullptr, nullptr, 384,
        gate_b, nullptr, 0, gatepre, nullptr, 384, 128, 80000);
    enhance_fuse_kernel<<<dim3(1250), blk, 0, stream>>>(
        delta, gatepre, radar, gamma, nh_hi);

    // conv 3x3 (MFMA, icb-outer/shift-inner) -> d_out; stats (4-way); bn
    conv_mfma_kernel<<<dim3(313, 2, 3), blk, 0, stream>>>(
        nh_hi, cwgt_hi, cwgt_lo, (float*)d_out);
    zero_stats_kernel<<<dim3(3), blk, 0, stream>>>();
    conv_stats_kernel<<<dim3(384, 4), blk, 0, stream>>>((const float*)d_out);
    bn_relu_kernel<<<dim3(30000), blk, 0, stream>>>(
        (float*)d_out, bn_g, bn_b);
}

// Round 7
// 1786.479 us; speedup vs baseline: 1.2092x; 1.2092x over previous
//
#include <hip/hip_runtime.h>
#include <hip/hip_bf16.h>

#define EPSF 1e-5f

typedef unsigned short u16;
typedef __attribute__((ext_vector_type(8))) short short8v;   // 8 bf16 bits (4 VGPRs)
typedef __attribute__((ext_vector_type(4))) float f32x4;

// ---------------------------------------------------------------------------
// Module-scope scratch. 84M floats = 336 MB, lifetime-aliased.
// Map (float offsets):
//   [       0,15360000) nh_hi  (bf16 [80000][384]: ch0-127 radar->enhanced, 128-383 image)
//   [15360000,30720000) nh_lo  (read by comb-proj; conv+gate read HI only)
//   [30720000,51200000) seq_comb fp32 [80000][256] -> hbuf (bf16 [80000][512]) after out-proj
//   [51200000,61440000) score/idx -> qh -> xbuf (fp32 80000x128)
//   [61440000,71680000) kvh fp32 [40000][256] -> gatepre fp32 [80000][128] (after attn)
//   [71680000,81920000) G: hscore fp32 [80000][128] -> kvn/qn/o/xn split-bf16 -> delta fp32
//   [81920000,82313216) WSEG: split weights (786432 u16 = 393216 floats)
//   [82330000,83657104) conv wgt hi/lo (2x1327104 u16)
//   [83900000,83900128) bias_pad (128 f, padded score_b1)
// d_out written ONLY by conv + bn_relu. d_ws unused. d_in never written.
// R4 lesson: simultaneous same-line misses from different XCDs don't merge —
// keep B-sharing tiles temporally separated (p-major gemm grid, hw-major conv).
// R6 lesson: conv icb-outer/shift-inner REGRESSED (946us, FETCH+50%, WRITE 2x;
// write-allocate interference not modeled) — conv loop order is LOCKED to
// shift-outer/icb-inner (562us measured) unless a dedicated probe says otherwise.
// ---------------------------------------------------------------------------
__device__ float g_arena[84000000];
__device__ float g_stats[768];

// ---------------------------------------------------------------------------
// helpers
// ---------------------------------------------------------------------------
__device__ __forceinline__ float wave_sum(float v) {
#pragma unroll
    for (int o = 32; o > 0; o >>= 1) v += __shfl_down(v, o, 64);
    return v;
}

// split fp32 -> bf16 hi + bf16 lo (lo = bf16(x - fp32(hi))); residual ~2^-17 rel
__device__ __forceinline__ void bf_split(float v, u16& h, u16& l) {
    __hip_bfloat16 bh = __float2bfloat16(v);
    float hv = __bfloat162float(bh);
    __hip_bfloat16 bl = __float2bfloat16(v - hv);
    h = *reinterpret_cast<u16*>(&bh);
    l = *reinterpret_cast<u16*>(&bl);
}

__device__ __forceinline__ void store_split4(u16* ph, u16* pl, float4 v) {
    u16 h0, l0, h1, l1, h2, l2, h3, l3;
    bf_split(v.x, h0, l0); bf_split(v.y, h1, l1);
    bf_split(v.z, h2, l2); bf_split(v.w, h3, l3);
    *(ushort4*)ph = make_ushort4(h0, h1, h2, h3);
    *(ushort4*)pl = make_ushort4(l0, l1, l2, l3);
}

// ---------------------------------------------------------------------------
// split_weights: all gemm weights -> WSEG split bf16 (hi|lo per segment).
//   inproj   0      49152  | outproj 98304 16384 | ffn1 131072 65536
//   ffn2     262144 65536  | delta  393216 16384 | gate 425984 49152
//   comb     524288 98304  (zero-padded [256][384])
//   score1   720896 32768  (zero-padded [128][256], rows 64-127 = 0)
// plus bias_pad[128] = score_b1 padded. 393344 threads -> grid 1537 x 256.
// ---------------------------------------------------------------------------
__global__ __launch_bounds__(256) void split_weights_kernel(
    const float* __restrict__ w_inproj, const float* __restrict__ w_outproj,
    const float* __restrict__ w_ffn1, const float* __restrict__ w_ffn2,
    const float* __restrict__ w_delta, const float* __restrict__ w_gate,
    const float* __restrict__ w_img, const float* __restrict__ w_rad,
    const float* __restrict__ w_sc1, const float* __restrict__ b_sc1,
    u16* __restrict__ wseg, float* __restrict__ bias_pad)
{
    int i = blockIdx.x * 256 + threadIdx.x;
    if (i >= 393344) return;
    if (i >= 393216) {                       // bias_pad
        int l = i - 393216;
        bias_pad[l] = (l < 64) ? b_sc1[l] : 0.f;
        return;
    }
    float v; int base, numel, local;
    if (i < 49152)       { local = i;          base = 0;      numel = 49152; v = w_inproj[local]; }
    else if (i < 65536)  { local = i - 49152;  base = 98304;  numel = 16384; v = w_outproj[local]; }
    else if (i < 131072) { local = i - 65536;  base = 131072; numel = 65536; v = w_ffn1[local]; }
    else if (i < 196608) { local = i - 131072; base = 262144; numel = 65536; v = w_ffn2[local]; }
    else if (i < 212992) { local = i - 196608; base = 393216; numel = 16384; v = w_delta[local]; }
    else if (i < 262144) { local = i - 212992; base = 425984; numel = 49152; v = w_gate[local]; }
    else if (i < 360448) {
        local = i - 262144; base = 524288; numel = 98304;
        int oc = local / 384, c = local - oc * 384;
        if (oc < 128) v = (c < 128) ? w_rad[oc * 128 + c] : 0.f;
        else          v = (c >= 128) ? w_img[(oc - 128) * 256 + (c - 128)] : 0.f;
    } else {
        local = i - 360448; base = 720896; numel = 32768;
        int oc = local / 256, c = local - oc * 256;
        v = (oc < 64) ? w_sc1[oc * 256 + c] : 0.f;
    }
    u16 hh, ll;
    bf_split(v, hh, ll);
    wseg[base + local] = hh;
    wseg[base + numel + local] = ll;
}

// ---------------------------------------------------------------------------
// mfma_gemm: out[p][ocb+oc] = sum_k B[p][k] * W[ocb+oc][k]  (+bias,+resid,relu)
// Grid: (ceil(P/128), Nout/128) — p-tiles FASTEST (R4 lesson).
// BMODE: 0 = split bf16 planes; 1 = single bf16 (no sBl -> 48 KB LDS, 3 blk/CU);
//        2 = fp32 split-on-the-fly
// OMODE: 0 = fp32 out; 1 = bf16 out.  resid has row stride rstride.
// ---------------------------------------------------------------------------
template <int BMODE, int OMODE, bool RELU>
__global__ __launch_bounds__(256, (BMODE == 1) ? 3 : 2) void mfma_gemm_kernel(
    const u16* __restrict__ Ah, const u16* __restrict__ Al,
    const u16* __restrict__ bh, const u16* __restrict__ bl,
    const float* __restrict__ bf, int bstride,
    const float* __restrict__ bias, const float* __restrict__ resid, int rstride,
    float* __restrict__ outf, u16* __restrict__ outh,
    int K, int Nout, int P)
{
    __shared__ alignas(16) u16 sAh[8192], sAl[8192], sBh[8192];
    __shared__ alignas(16) u16 sBl[(BMODE != 1) ? 8192 : 8];

    const int tid  = threadIdx.x;
    const int lane = tid & 63;
    const int wid  = tid >> 6;
    const int wrm  = wid >> 1;
    const int wcn  = wid & 1;
    const int p0   = blockIdx.x * 128;
    const int ocb  = blockIdx.y * 128;

    const int r0  = tid >> 3;
    const int cl  = tid & 7;
    const int swz = cl ^ (r0 & 7);

    f32x4 acc[4][4];
#pragma unroll
    for (int i = 0; i < 4; ++i)
#pragma unroll
        for (int j = 0; j < 4; ++j) acc[i][j] = (f32x4){0.f, 0.f, 0.f, 0.f};

    const int fr = lane & 15;
    const int fc = lane >> 4;

    for (int kk = 0; kk < K; kk += 64) {
        __syncthreads();
#pragma unroll
        for (int k = 0; k < 4; ++k) {
            int row = r0 + k * 32;
            int di = row * 64 + swz * 8;
            size_t ga = (size_t)(ocb + row) * K + kk + cl * 8;
            *(short8v*)&sAh[di] = *(const short8v*)&Ah[ga];
            *(short8v*)&sAl[di] = *(const short8v*)&Al[ga];
            int p = p0 + row;
            if (BMODE == 0) {
                if (p < P) {
                    size_t gb = (size_t)p * bstride + kk + cl * 8;
                    *(short8v*)&sBh[di] = *(const short8v*)&bh[gb];
                    *(short8v*)&sBl[di] = *(const short8v*)&bl[gb];
                } else {
                    short8v z = {0,0,0,0,0,0,0,0};
                    *(short8v*)&sBh[di] = z;
                    *(short8v*)&sBl[di] = z;
                }
            } else if (BMODE == 1) {
                if (p < P) {
                    size_t gb = (size_t)p * bstride + kk + cl * 8;
                    *(short8v*)&sBh[di] = *(const short8v*)&bh[gb];
                } else {
                    short8v z = {0,0,0,0,0,0,0,0};
                    *(short8v*)&sBh[di] = z;
                }
            } else {
                short8v vh8 = {0,0,0,0,0,0,0,0}, vl8 = {0,0,0,0,0,0,0,0};
                if (p < P) {
                    const float* src = bf + (size_t)p * bstride + kk + cl * 8;
                    float4 f0 = *(const float4*)(src);
                    float4 f1 = *(const float4*)(src + 4);
                    float fv[8] = {f0.x, f0.y, f0.z, f0.w, f1.x, f1.y, f1.z, f1.w};
#pragma unroll
                    for (int j = 0; j < 8; ++j) {
                        u16 hh, ll;
                        bf_split(fv[j], hh, ll);
                        vh8[j] = (short)hh;
                        vl8[j] = (short)ll;
                    }
                }
                *(short8v*)&sBh[di] = vh8;
                *(short8v*)&sBl[di] = vl8;
            }
        }
        __syncthreads();
#pragma unroll
        for (int h = 0; h < 2; ++h) {
            const int kc = h * 4 + fc;
            short8v bhf[4], blf[4];
#pragma unroll
            for (int nn = 0; nn < 4; ++nn) {
                int row = wcn * 64 + nn * 16 + fr;
                int idx = row * 64 + ((kc ^ (row & 7)) << 3);
                bhf[nn] = *(const short8v*)&sBh[idx];
                if (BMODE != 1) blf[nn] = *(const short8v*)&sBl[idx];
            }
#pragma unroll
            for (int mm = 0; mm < 4; ++mm) {
                int row = wrm * 64 + mm * 16 + fr;
                int idx = row * 64 + ((kc ^ (row & 7)) << 3);
                short8v ahf = *(const short8v*)&sAh[idx];
                short8v alf = *(const short8v*)&sAl[idx];
#pragma unroll
                for (int nn = 0; nn < 4; ++nn)
                    acc[mm][nn] = __builtin_amdgcn_mfma_f32_16x16x32_bf16(
                        ahf, bhf[nn], acc[mm][nn], 0, 0, 0);
                if (BMODE != 1) {
#pragma unroll
                    for (int nn = 0; nn < 4; ++nn)
                        acc[mm][nn] = __builtin_amdgcn_mfma_f32_16x16x32_bf16(
                            ahf, blf[nn], acc[mm][nn], 0, 0, 0);
                }
#pragma unroll
                for (int nn = 0; nn < 4; ++nn)
                    acc[mm][nn] = __builtin_amdgcn_mfma_f32_16x16x32_bf16(
                        alf, bhf[nn], acc[mm][nn], 0, 0, 0);
            }
        }
    }

    // epilogue: D[row=oc][col=pos] -> out[p][oc], 4 regs = 4 consecutive oc
#pragma unroll
    for (int mm = 0; mm < 4; ++mm) {
        int base = ocb + wrm * 64 + mm * 16 + fc * 4;
        float4 bv = {0.f, 0.f, 0.f, 0.f};
        if (bias) bv = *(const float4*)&bias[base];
#pragma unroll
        for (int nn = 0; nn < 4; ++nn) {
            int p = p0 + wcn * 64 + nn * 16 + fr;
            if (p < P) {
                size_t row = (size_t)p * Nout + base;
                float4 r;
                r.x = acc[mm][nn][0] + bv.x;
                r.y = acc[mm][nn][1] + bv.y;
                r.z = acc[mm][nn][2] + bv.z;
                r.w = acc[mm][nn][3] + bv.w;
                if (resid) {
                    float4 rr = *(const float4*)&resid[(size_t)p * rstride + base - ocb];
                    r.x += rr.x; r.y += rr.y; r.z += rr.z; r.w += rr.w;
                }
                if (RELU) {
                    r.x = fmaxf(r.x, 0.f); r.y = fmaxf(r.y, 0.f);
                    r.z = fmaxf(r.z, 0.f); r.w = fmaxf(r.w, 0.f);
                }
                if (OMODE == 0) {
                    *(float4*)&outf[row] = r;
                } else {
                    __hip_bfloat16 b0 = __float2bfloat16(r.x);
                    __hip_bfloat16 b1 = __float2bfloat16(r.y);
                    __hip_bfloat16 b2 = __float2bfloat16(r.z);
                    __hip_bfloat16 b3 = __float2bfloat16(r.w);
                    *(ushort4*)&outh[row] = make_ushort4(
                        *reinterpret_cast<u16*>(&b0), *reinterpret_cast<u16*>(&b1),
                        *reinterpret_cast<u16*>(&b2), *reinterpret_cast<u16*>(&b3));
                }
            }
        }
    }
}

// ---------------------------------------------------------------------------
// score_reduce: score[p] = h[p][0:64] . w2 + b2  (h from MFMA score-gemm)
// ---------------------------------------------------------------------------
__global__ __launch_bounds__(256) void score_reduce_kernel(
    const float* __restrict__ h, const float* __restrict__ w2,
    const float* __restrict__ b2, float* __restrict__ score)
{
    int p = blockIdx.x * 4 + (threadIdx.x >> 6);
    int l = threadIdx.x & 63;
    float v = h[(size_t)p * 128 + l] * w2[l];
    v = wave_sum(v);
    if (l == 0) score[p] = v + b2[0];
}

// ---------------------------------------------------------------------------
// topk: exact stable rank selection (matches jax.lax.top_k tie-breaking)
// ---------------------------------------------------------------------------
__global__ __launch_bounds__(256) void topk_kernel(
    const float* __restrict__ score, int* __restrict__ idx)
{
    __shared__ float s[200];
    const int n = blockIdx.x;
    const int t = threadIdx.x;
    if (t < 200) s[t] = score[(size_t)n * 200 + t];
    __syncthreads();
    if (t < 200) {
        float my = s[t];
        int cnt = 0;
        for (int j = 0; j < 200; j++) {
            float o = s[j];
            cnt += (o > my) || (o == my && j < t);
        }
        if (cnt < 100) idx[n * 100 + cnt] = t;
    }
}

// ---------------------------------------------------------------------------
// ln_gather: out[r][:] = LN(in[src_row][:]) * g + b  -> split bf16 planes
// ---------------------------------------------------------------------------
__global__ __launch_bounds__(256) void ln_gather_kernel(
    const float* __restrict__ in, int stride, const int* __restrict__ gidx,
    const float* __restrict__ g, const float* __restrict__ bb,
    u16* __restrict__ oh, u16* __restrict__ ol)
{
    __shared__ float red[4];
    const int tid = threadIdx.x;
    const int grp = tid >> 7;
    const int t = tid & 127;
    const int r = blockIdx.x * 2 + grp;

    size_t src_row;
    if (gidx) src_row = (size_t)(r / 100) * 200 + gidx[r];
    else      src_row = (size_t)r;

    float x = in[src_row * stride + t];
    float s = wave_sum(x);
    if ((tid & 63) == 0) red[tid >> 6] = s;
    __syncthreads();
    float m = (red[grp * 2] + red[grp * 2 + 1]) * 0.0078125f;
    float d = x - m;
    float s2 = wave_sum(d * d);
    __syncthreads();
    if ((tid & 63) == 0) red[tid >> 6] = s2;
    __syncthreads();
    float var = (red[grp * 2] + red[grp * 2 + 1]) * 0.0078125f;
    float y = d * rsqrtf(var + EPSF) * g[t] + bb[t];
    u16 hh, ll;
    bf_split(y, hh, ll);
    oh[(size_t)r * 128 + t] = hh;
    ol[(size_t)r * 128 + t] = ll;
}

// ---------------------------------------------------------------------------
// attention: block = (head h, row n); thread = one query w (<200)
// K/V interleaved in kvh [40000][256]; outputs split bf16 planes
// ---------------------------------------------------------------------------
__global__ __launch_bounds__(256) void attention_kernel(
    const float* __restrict__ qh, const float* __restrict__ kvh,
    u16* __restrict__ o_hi, u16* __restrict__ o_lo)
{
    __shared__ float sk[100][16];
    __shared__ float sv[100][16];
    const int h = blockIdx.x;
    const int n = blockIdx.y;
    const int tid = threadIdx.x;

    for (int e = tid; e < 1600; e += 256) {
        int kk = e >> 4, d = e & 15;
        size_t src = ((size_t)n * 100 + kk) * 256 + h * 16 + d;
        sk[kk][d] = kvh[src];
        sv[kk][d] = kvh[src + 128];
    }
    __syncthreads();

    if (tid < 200) {
        const float* qp = &qh[((size_t)n * 200 + tid) * 128 + h * 16];
        float4 q0 = *(const float4*)(qp + 0);
        float4 q1 = *(const float4*)(qp + 4);
        float4 q2 = *(const float4*)(qp + 8);
        float4 q3 = *(const float4*)(qp + 12);

        float m = -INFINITY, l = 0.f;
        float4 a0 = {0,0,0,0}, a1 = {0,0,0,0}, a2 = {0,0,0,0}, a3 = {0,0,0,0};

        for (int kk = 0; kk < 100; kk++) {
            const float4* kp = (const float4*)&sk[kk][0];
            float s = q0.x*kp[0].x + q0.y*kp[0].y + q0.z*kp[0].z + q0.w*kp[0].w
                    + q1.x*kp[1].x + q1.y*kp[1].y + q1.z*kp[1].z + q1.w*kp[1].w
                    + q2.x*kp[2].x + q2.y*kp[2].y + q2.z*kp[2].z + q2.w*kp[2].w
                    + q3.x*kp[3].x + q3.y*kp[3].y + q3.z*kp[3].z + q3.w*kp[3].w;
            s *= 0.25f;
            float nm = fmaxf(m, s);
            float corr = __expf(m - nm);
            float pe = __expf(s - nm);
            l = l * corr + pe;
            const float4* vp = (const float4*)&sv[kk][0];
            float4 v0 = vp[0], v1 = vp[1], v2 = vp[2], v3 = vp[3];
            a0.x = a0.x * corr + pe * v0.x; a0.y = a0.y * corr + pe * v0.y;
            a0.z = a0.z * corr + pe * v0.z; a0.w = a0.w * corr + pe * v0.w;
            a1.x = a1.x * corr + pe * v1.x; a1.y = a1.y * corr + pe * v1.y;
            a1.z = a1.z * corr + pe * v1.z; a1.w = a1.w * corr + pe * v1.w;
            a2.x = a2.x * corr + pe * v2.x; a2.y = a2.y * corr + pe * v2.y;
            a2.z = a2.z * corr + pe * v2.z; a2.w = a2.w * corr + pe * v2.w;
            a3.x = a3.x * corr + pe * v3.x; a3.y = a3.y * corr + pe * v3.y;
            a3.z = a3.z * corr + pe * v3.z; a3.w = a3.w * corr + pe * v3.w;
            m = nm;
        }
        float inv = 1.f / l;
        a0.x *= inv; a0.y *= inv; a0.z *= inv; a0.w *= inv;
        a1.x *= inv; a1.y *= inv; a1.z *= inv; a1.w *= inv;
        a2.x *= inv; a2.y *= inv; a2.z *= inv; a2.w *= inv;
        a3.x *= inv; a3.y *= inv; a3.z *= inv; a3.w *= inv;
        size_t ob = ((size_t)n * 200 + tid) * 128 + h * 16;
        store_split4(&o_hi[ob + 0],  &o_lo[ob + 0],  a0);
        store_split4(&o_hi[ob + 4],  &o_lo[ob + 4],  a1);
        store_split4(&o_hi[ob + 8],  &o_lo[ob + 8],  a2);
        store_split4(&o_hi[ob + 12], &o_lo[ob + 12], a3);
    }
}

// ---------------------------------------------------------------------------
// prep_weights: fuse_w [oc][ic][ky][kx] fp32 -> conv wgt hi/lo [oc][s][ic] bf16
// ---------------------------------------------------------------------------
__global__ __launch_bounds__(256) void prep_weights_kernel(
    const float* __restrict__ fw, u16* __restrict__ wh, u16* __restrict__ wl)
{
    int idx = blockIdx.x * 256 + threadIdx.x;   // < 384*384 = 147456
    int oc = idx / 384;
    int ic = idx - oc * 384;
    const float* src = fw + (size_t)idx * 9;
    u16* dh = wh + (size_t)oc * 3456 + ic;
    u16* dl = wl + (size_t)oc * 3456 + ic;
#pragma unroll
    for (int s = 0; s < 9; ++s) {
        u16 hh, ll;
        bf_split(src[s], hh, ll);
        dh[(size_t)s * 384] = hh;
        dl[(size_t)s * 384] = ll;
    }
}

// ---------------------------------------------------------------------------
// convert_nhwc: concat(radar[0:128], image[0:256]) NCHW fp32 -> NHWC bf16 split
// ---------------------------------------------------------------------------
__global__ __launch_bounds__(256) void convert_nhwc_kernel(
    const float* __restrict__ radar, const float* __restrict__ image,
    u16* __restrict__ oh, u16* __restrict__ ol)
{
    int p = blockIdx.x * 256 + threadIdx.x;
    if (p >= 80000) return;
    int cg = blockIdx.y;               // 0..5 -> channels [cg*64, cg*64+64)
    int b = p >= 40000 ? 1 : 0;
    int hw = p - b * 40000;
    u16* ph = oh + (size_t)p * 384 + cg * 64;
    u16* pl = ol + (size_t)p * 384 + cg * 64;
#pragma unroll 1
    for (int g = 0; g < 8; ++g) {
        short8v vh, vl;
#pragma unroll
        for (int j = 0; j < 8; ++j) {
            int c = cg * 64 + g * 8 + j;
            float v = (c < 128)
                ? radar[((size_t)(b * 128 + c)) * 40000 + hw]
                : image[((size_t)(b * 256 + (c - 128))) * 40000 + hw];
            u16 hh, ll;
            bf_split(v, hh, ll);
            vh[j] = (short)hh;
            vl[j] = (short)ll;
        }
        *(short8v*)&ph[g * 8] = vh;
        *(short8v*)&pl[g * 8] = vl;
    }
}

// ---------------------------------------------------------------------------
// enhance_fuse: nh[p][0:128] = bf16(radar + gamma*sigmoid(gatepre)*rmask*delta)
// HI plane only — nh_lo radar chunk is dead (conv + gate read hi only).
// ---------------------------------------------------------------------------
__global__ __launch_bounds__(256) void enhance_fuse_kernel(
    const float* __restrict__ delta, const float* __restrict__ gatepre,
    const float* __restrict__ radar, const float* __restrict__ gamma_p,
    u16* __restrict__ nh)
{
    __shared__ float srad[64][136];   // [pos][oc], padded
    const int tid = threadIdx.x;
    const int blk = blockIdx.x;        // 0..1249 (625 per b)
    const int b = blk >= 625 ? 1 : 0;
    const int hw0 = (blk - b * 625) * 64;
    const int p0 = b * 40000 + hw0;

#pragma unroll
    for (int i = 0; i < 32; ++i) {
        int e = tid + i * 256;         // 8192 elems
        int oc = e >> 6, pos = e & 63;
        srad[pos][oc] = radar[((size_t)(b * 128 + oc)) * 40000 + hw0 + pos];
    }
    __syncthreads();

    const float gmm = gamma_p[0];
    const int c4 = tid & 31;           // oc quad index
    const int rr = tid >> 5;           // 0..7
#pragma unroll
    for (int j = 0; j < 8; ++j) {
        int pos = j * 8 + rr;
        int p = p0 + pos;
        int hw = hw0 + pos;
        int hrow = hw / 200;
        float rm = fmaxf(0.3f, 1.0f - 0.7f * ((float)hrow * (1.0f / 199.0f)));
        float4 dv = *(const float4*)&delta[(size_t)p * 128 + c4 * 4];
        float4 gv = *(const float4*)&gatepre[(size_t)p * 128 + c4 * 4];
        float4 rv = *(const float4*)&srad[pos][c4 * 4];
        float rx = rv.x + gmm * (1.f / (1.f + __expf(-gv.x))) * rm * dv.x;
        float ry = rv.y + gmm * (1.f / (1.f + __expf(-gv.y))) * rm * dv.y;
        float rz = rv.z + gmm * (1.f / (1.f + __expf(-gv.z))) * rm * dv.z;
        float rw = rv.w + gmm * (1.f / (1.f + __expf(-gv.w))) * rm * dv.w;
        __hip_bfloat16 b0 = __float2bfloat16(rx);
        __hip_bfloat16 b1 = __float2bfloat16(ry);
        __hip_bfloat16 b2 = __float2bfloat16(rz);
        __hip_bfloat16 b3 = __float2bfloat16(rw);
        *(ushort4*)&nh[(size_t)p * 384 + c4 * 4] = make_ushort4(
            *reinterpret_cast<u16*>(&b0), *reinterpret_cast<u16*>(&b1),
            *reinterpret_cast<u16*>(&b2), *reinterpret_cast<u16*>(&b3));
    }
}

// ---------------------------------------------------------------------------
// conv_mfma: 3x3 SAME conv as 9 shifted GEMMs on matrix cores.
// R5-EXACT structure (562us measured): shift OUTER, icb INNER. Do not reorder
// (R6 lesson). Input = HI bf16 plane only (2 MFMA products). LDS 48 KB ->
// 3 blocks/CU. Grid (313,2,3) hw-major (R4 lesson).
// ---------------------------------------------------------------------------
__global__ __launch_bounds__(256, 3) void conv_mfma_kernel(
    const u16* __restrict__ nhwc_hi,
    const u16* __restrict__ wgt_hi,  const u16* __restrict__ wgt_lo,
    float* __restrict__ out)
{
    __shared__ alignas(16) u16 sAh[8192], sAl[8192], sBh[8192];  // 48 KB

    const int tid  = threadIdx.x;
    const int lane = tid & 63;
    const int wid  = tid >> 6;
    const int wrm  = wid >> 1;
    const int wcn  = wid & 1;
    const int hw0  = blockIdx.x * 128;
    const int b    = blockIdx.y;
    const int oc0  = blockIdx.z * 128;

    const int r0  = tid >> 3;
    const int cl  = tid & 7;
    const int swz = cl ^ (r0 & 7);

    const int y0 = hw0 / 200;
    const int x0 = hw0 - y0 * 200;

    f32x4 acc[4][4];
#pragma unroll
    for (int i = 0; i < 4; ++i)
#pragma unroll
        for (int j = 0; j < 4; ++j) acc[i][j] = (f32x4){0.f, 0.f, 0.f, 0.f};

    size_t abase[4];
#pragma unroll
    for (int k = 0; k < 4; ++k)
        abase[k] = (size_t)(oc0 + r0 + k * 32) * 3456 + cl * 8;

    const int fr = lane & 15;
    const int fc = lane >> 4;

    for (int s = 0; s < 9; ++s) {
        const int dy = s / 3 - 1;
        const int dx = s % 3 - 1;
        size_t bsrc[4];
        int bval[4];
#pragma unroll
        for (int k = 0; k < 4; ++k) {
            int row = r0 + k * 32;
            int hwo = hw0 + row;
            int xr  = x0 + row;
            int wrp = (xr >= 200) ? 1 : 0;
            int yy  = y0 + wrp + dy;
            int xx  = xr - wrp * 200 + dx;
            int v = (hwo < 40000) && ((unsigned)yy < 200u) && ((unsigned)xx < 200u);
            bval[k] = v;
            bsrc[k] = v ? ((size_t)(b * 40000 + yy * 200 + xx) * 384 + cl * 8) : 0;
        }
        const size_t wofs = (size_t)s * 384;

        for (int icb = 0; icb < 6; ++icb) {
            const int ic0 = icb * 64;
            __syncthreads();
#pragma unroll
            for (int k = 0; k < 4; ++k) {
                int di = (r0 + k * 32) * 64 + swz * 8;
                size_t ga = abase[k] + wofs + ic0;
                *(short8v*)&sAh[di] = *(const short8v*)&wgt_hi[ga];
                *(short8v*)&sAl[di] = *(const short8v*)&wgt_lo[ga];
                if (bval[k]) {
                    *(short8v*)&sBh[di] = *(const short8v*)&nhwc_hi[bsrc[k] + ic0];
                } else {
                    short8v z = {0, 0, 0, 0, 0, 0, 0, 0};
                    *(short8v*)&sBh[di] = z;
                }
            }
            __syncthreads();
#pragma unroll
            for (int h = 0; h < 2; ++h) {
                const int kc = h * 4 + fc;
                short8v bhf[4];
#pragma unroll
                for (int nn = 0; nn < 4; ++nn) {
                    int row = wcn * 64 + nn * 16 + fr;
                    int idx = row * 64 + ((kc ^ (row & 7)) << 3);
                    bhf[nn] = *(const short8v*)&sBh[idx];
                }
#pragma unroll
                for (int mm = 0; mm < 4; ++mm) {
                    int row = wrm * 64 + mm * 16 + fr;
                    int idx = row * 64 + ((kc ^ (row & 7)) << 3);
                    short8v ahf = *(const short8v*)&sAh[idx];
                    short8v alf = *(const short8v*)&sAl[idx];
#pragma unroll
                    for (int nn = 0; nn < 4; ++nn)
                        acc[mm][nn] = __builtin_amdgcn_mfma_f32_16x16x32_bf16(
                            ahf, bhf[nn], acc[mm][nn], 0, 0, 0);
#pragma unroll
                    for (int nn = 0; nn < 4; ++nn)
                        acc[mm][nn] = __builtin_amdgcn_mfma_f32_16x16x32_bf16(
                            alf, bhf[nn], acc[mm][nn], 0, 0, 0);
                }
            }
        }
    }

#pragma unroll
    for (int mm = 0; mm < 4; ++mm) {
        int oc = oc0 + wrm * 64 + mm * 16 + fc * 4;
#pragma unroll
        for (int nn = 0; nn < 4; ++nn) {
            int p = hw0 + wcn * 64 + nn * 16 + fr;
            if (p < 40000) {
                float* op = out + (size_t)(b * 384 + oc) * 40000 + p;
#pragma unroll
                for (int r = 0; r < 4; ++r)
                    op[(size_t)r * 40000] = acc[mm][nn][r];
            }
        }
    }
}

// ---------------------------------------------------------------------------
// zero_stats + conv_stats (4 hw-chunks per channel, atomic accumulate)
// ---------------------------------------------------------------------------
__global__ void zero_stats_kernel() {
    int i = blockIdx.x * 256 + threadIdx.x;
    if (i < 768) g_stats[i] = 0.f;
}

__global__ __launch_bounds__(256) void conv_stats_kernel(const float* __restrict__ out)
{
    const int c = blockIdx.x;           // 0..383
    const int chunk = blockIdx.y;       // 0..3
    float s1 = 0.f, s2 = 0.f;
#pragma unroll
    for (int b = 0; b < 2; ++b) {
        const float4* pp = (const float4*)(out + (size_t)(b * 384 + c) * 40000)
                         + (size_t)chunk * 2500;
        for (int i = threadIdx.x; i < 2500; i += 256) {
            float4 v = pp[i];
            s1 += v.x + v.y + v.z + v.w;
            s2 += v.x * v.x + v.y * v.y + v.z * v.z + v.w * v.w;
        }
    }
    s1 = wave_sum(s1);
    s2 = wave_sum(s2);
    __shared__ float r1[4], r2[4];
    if ((threadIdx.x & 63) == 0) {
        r1[threadIdx.x >> 6] = s1;
        r2[threadIdx.x >> 6] = s2;
    }
    __syncthreads();
    if (threadIdx.x == 0) {
        atomicAdd(&g_stats[c * 2],     r1[0] + r1[1] + r1[2] + r1[3]);
        atomicAdd(&g_stats[c * 2 + 1], r2[0] + r2[1] + r2[2] + r2[3]);
    }
}

// ---------------------------------------------------------------------------
// bn_relu: in-place on d_out
// ---------------------------------------------------------------------------
__global__ __launch_bounds__(256) void bn_relu_kernel(
    float* __restrict__ out, const float* __restrict__ g,
    const float* __restrict__ bb)
{
    int i = blockIdx.x * 256 + threadIdx.x;   // float4 index < 7,680,000
    int flat = i * 4;
    int oc = (flat / 40000) % 384;
    float m = g_stats[oc * 2] * (1.f / 80000.f);
    float v = g_stats[oc * 2 + 1] * (1.f / 80000.f) - m * m;
    float inv = rsqrtf(v + EPSF);
    float sc = g[oc] * inv;
    float sh = bb[oc] - m * sc;
    float4 c = ((float4*)out)[i];
    c.x = fmaxf(c.x * sc + sh, 0.f);
    c.y = fmaxf(c.y * sc + sh, 0.f);
    c.z = fmaxf(c.z * sc + sh, 0.f);
    c.w = fmaxf(c.w * sc + sh, 0.f);
    ((float4*)out)[i] = c;
}

// ---------------------------------------------------------------------------
// launch
// ---------------------------------------------------------------------------
extern "C" void kernel_launch(void* const* d_in, const int* in_sizes, int n_in,
                              void* d_out, int out_size, void* d_ws, size_t ws_size,
                              hipStream_t stream)
{
    (void)in_sizes; (void)n_in; (void)out_size; (void)d_ws; (void)ws_size;

    const float* radar      = (const float*)d_in[0];
    const float* image      = (const float*)d_in[1];
    const float* img_proj_w = (const float*)d_in[2];
    const float* rad_proj_w = (const float*)d_in[3];
    const float* in_proj_w  = (const float*)d_in[4];
    const float* in_proj_b  = (const float*)d_in[5];
    const float* out_proj_w = (const float*)d_in[6];
    const float* out_proj_b = (const float*)d_in[7];
    const float* ln1q_g     = (const float*)d_in[8];
    const float* ln1q_b     = (const float*)d_in[9];
    const float* ln1kv_g    = (const float*)d_in[10];
    const float* ln1kv_b    = (const float*)d_in[11];
    const float* ln2_g      = (const float*)d_in[12];
    const float* ln2_b      = (const float*)d_in[13];
    const float* ffn_w1     = (const float*)d_in[14];
    const float* ffn_b1     = (const float*)d_in[15];
    const float* ffn_w2     = (const float*)d_in[16];
    const float* ffn_b2     = (const float*)d_in[17];
    const float* score_w1   = (const float*)d_in[18];
    const float* score_b1   = (const float*)d_in[19];
    const float* score_w2   = (const float*)d_in[20];
    const float* score_b2   = (const float*)d_in[21];
    const float* rad_delta_w= (const float*)d_in[22];
    const float* gamma      = (const float*)d_in[23];
    const float* gate_w     = (const float*)d_in[24];
    const float* gate_b     = (const float*)d_in[25];
    const float* fuse_w     = (const float*)d_in[26];
    const float* bn_g       = (const float*)d_in[27];
    const float* bn_b       = (const float*)d_in[28];

    float* arena = nullptr;
    hipGetSymbolAddress((void**)&arena, HIP_SYMBOL(g_arena));

    // --- arena regions (see map above) ---
    u16*   nh_hi    = (u16*)arena;                      // [80000][384] hi
    u16*   nh_lo    = (u16*)(arena + 15360000);         // [80000][384] lo
    float* seq_comb = arena + 30720000;                 // [80000][256] fp32
    float* score    = arena + 51200000;                 // 80000 f
    int*   idx      = (int*)(arena + 51280000);         // 40000 int
    float* qh       = arena + 51200000;                 // overlays score/idx
    float* xbuf     = arena + 51200000;                 // overlays qh
    float* kvh      = arena + 61440000;                 // [40000][256] fp32
    float* gatepre  = arena + 61440000;                 // [80000][128] over kvh (after attn)
    float* hscore   = arena + 71680000;                 // [80000][128] fp32 (score MLP hidden)
    u16*   gbase    = (u16*)(arena + 71680000);         // split-plane region G (over dead hscore)
    u16*   kvn_hi   = gbase,            *kvn_lo = gbase + 5120000;   // [40000][128]
    u16*   qn_hi    = gbase,            *qn_lo  = gbase + 10240000;  // [80000][128]
    u16*   o_hi     = gbase,            *o_lo   = gbase + 10240000;  // [80000][128]
    u16*   xn_hi    = gbase,            *xn_lo  = gbase + 10240000;  // [80000][128]
    float* delta    = arena + 71680000;                 // [80000][128] over G
    u16*   hbuf     = (u16*)(arena + 30720000);         // [80000][512] bf16 over seq_comb
    u16*   wseg     = (u16*)(arena + 81920000);         // 786432 u16 -> ends 82313216 f
    u16*   cwgt_hi  = (u16*)(arena + 82330000);         // conv wgt
    u16*   cwgt_lo  = cwgt_hi + 1327104;                // ends 83657104 f
    float* bias_pad = arena + 83900000;                 // 128 f (padded score_b1)

    // split-weight sub-pointers (u16 offsets within wseg)
    const u16* w_q_hi    = wseg + 0,      *w_q_lo    = wseg + 49152;          // in_proj rows 0-127
    const u16* w_kv_hi   = wseg + 16384,  *w_kv_lo   = wseg + 49152 + 16384;  // rows 128-383 (256)
    const u16* w_out_hi  = wseg + 98304,  *w_out_lo  = wseg + 114688;
    const u16* w_ffn1_hi = wseg + 131072, *w_ffn1_lo = wseg + 196608;
    const u16* w_ffn2_hi = wseg + 262144, *w_ffn2_lo = wseg + 327680;
    const u16* w_dlt_hi  = wseg + 393216, *w_dlt_lo  = wseg + 409600;
    const u16* w_gate_hi = wseg + 425984, *w_gate_lo = wseg + 475136;
    const u16* w_comb_hi = wseg + 524288, *w_comb_lo = wseg + 622592;         // [256][384] padded
    const u16* w_sc1_hi  = wseg + 720896, *w_sc1_lo  = wseg + 753664;         // [128][256] padded

    const dim3 blk(256);

    // prep: weight splits + NHWC conversion of (radar|image)
    split_weights_kernel<<<dim3(1537), blk, 0, stream>>>(
        in_proj_w, out_proj_w, ffn_w1, ffn_w2, rad_delta_w, gate_w,
        img_proj_w, rad_proj_w, score_w1, score_b1, wseg, bias_pad);
    prep_weights_kernel<<<dim3(576), blk, 0, stream>>>(fuse_w, cwgt_hi, cwgt_lo);
    convert_nhwc_kernel<<<dim3(313, 6), blk, 0, stream>>>(radar, image, nh_hi, nh_lo);

    // combined projection: seq_comb[p][0:128]=rad, [128:256]=img
    mfma_gemm_kernel<0, 0, false><<<dim3(625, 2), blk, 0, stream>>>(
        w_comb_hi, w_comb_lo, nh_hi, nh_lo, nullptr, 384,
        nullptr, nullptr, 0, seq_comb, nullptr, 384, 256, 80000);

    // scoring MLP (MFMA, padded W1/bias) -> hscore; reduce with w2; top-k
    mfma_gemm_kernel<2, 0, true><<<dim3(625, 1), blk, 0, stream>>>(
        w_sc1_hi, w_sc1_lo, nullptr, nullptr, seq_comb, 256,
        bias_pad, nullptr, 0, hscore, nullptr, 256, 128, 80000);
    score_reduce_kernel<<<dim3(20000), blk, 0, stream>>>(
        hscore, score_w2, score_b2, score);
    topk_kernel<<<dim3(400), blk, 0, stream>>>(score, idx);

    // gathered LN(kv) -> kvn planes (over dead hscore); merged K+V projection
    ln_gather_kernel<<<dim3(20000), blk, 0, stream>>>(
        seq_comb + 128, 256, idx, ln1kv_g, ln1kv_b, kvn_hi, kvn_lo);
    mfma_gemm_kernel<0, 0, false><<<dim3(313, 2), blk, 0, stream>>>(
        w_kv_hi, w_kv_lo, kvn_hi, kvn_lo, nullptr, 128,
        in_proj_b + 128, nullptr, 0, kvh, nullptr, 128, 256, 40000);

    // LN(q) -> qn planes (over dead kvn), Q projection -> qh (over dead score/idx)
    ln_gather_kernel<<<dim3(40000), blk, 0, stream>>>(
        seq_comb, 256, nullptr, ln1q_g, ln1q_b, qn_hi, qn_lo);
    mfma_gemm_kernel<0, 0, false><<<dim3(625, 1), blk, 0, stream>>>(
        w_q_hi, w_q_lo, qn_hi, qn_lo, nullptr, 128,
        in_proj_b, nullptr, 0, qh, nullptr, 128, 128, 80000);

    // attention -> o planes (over dead qn)
    attention_kernel<<<dim3(8, 400), blk, 0, stream>>>(qh, kvh, o_hi, o_lo);

    // out-proj + residual (rad part of seq_comb, rstride 256) -> xbuf
    mfma_gemm_kernel<0, 0, false><<<dim3(625, 1), blk, 0, stream>>>(
        w_out_hi, w_out_lo, o_hi, o_lo, nullptr, 128,
        out_proj_b, seq_comb, 256, xbuf, nullptr, 128, 128, 80000);

    // FFN: ln2 -> xn planes (over dead o); FFN1 -> hbuf bf16 (over dead seq_comb);
    // FFN2 -> xbuf in place
    ln_gather_kernel<<<dim3(40000), blk, 0, stream>>>(
        xbuf, 128, nullptr, ln2_g, ln2_b, xn_hi, xn_lo);
    mfma_gemm_kernel<0, 1, true><<<dim3(625, 4), blk, 0, stream>>>(
        w_ffn1_hi, w_ffn1_lo, xn_hi, xn_lo, nullptr, 128,
        ffn_b1, nullptr, 0, nullptr, hbuf, 128, 512, 80000);
    mfma_gemm_kernel<1, 0, false><<<dim3(625, 1), blk, 0, stream>>>(
        w_ffn2_hi, w_ffn2_lo, hbuf, nullptr, nullptr, 512,
        ffn_b2, xbuf, 128, xbuf, nullptr, 512, 128, 80000);

    // enhance: delta gemm (fp32 B, over dead xn) + gate gemm (hi-only B, over
    // dead kvh) + fused sigmoid/rmask/residual writing nh radar channels
    mfma_gemm_kernel<2, 0, false><<<dim3(625, 1), blk, 0, stream>>>(
        w_dlt_hi, w_dlt_lo, nullptr, nullptr, xbuf, 128,
        nullptr, nullptr, 0, delta, nullptr, 128, 128, 80000);
    mfma_gemm_kernel<1, 0, false><<<dim3(625, 1), blk, 0, stream>>>(
        w_gate_hi, w_gate_lo, nh_hi, nullptr, nullptr, 384,
        gate_b, nullptr, 0, gatepre, nullptr, 384, 128, 80000);
    enhance_fuse_kernel<<<dim3(1250), blk, 0, stream>>>(
        delta, gatepre, radar, gamma, nh_hi);

    // conv 3x3 (MFMA, R5-exact loop order) -> d_out; stats (4-way); bn
    conv_mfma_kernel<<<dim3(313, 2, 3), blk, 0, stream>>>(
        nh_hi, cwgt_hi, cwgt_lo, (float*)d_out);
    zero_stats_kernel<<<dim3(3), blk, 0, stream>>>();
    conv_stats_kernel<<<dim3(384, 4), blk, 0, stream>>>((const float*)d_out);
    bn_relu_kernel<<<dim3(30000), blk, 0, stream>>>(
        (float*)d_out, bn_g, bn_b);
}

// Round 8
// 1504.124 us; speedup vs baseline: 1.4361x; 1.1877x over previous
//
#include <hip/hip_runtime.h>
#include <hip/hip_bf16.h>

#define EPSF 1e-5f

typedef unsigned short u16;
typedef unsigned int u32;
typedef __attribute__((ext_vector_type(8))) short short8v;   // 8 bf16 bits (4 VGPRs)
typedef __attribute__((ext_vector_type(4))) float f32x4;

// ---------------------------------------------------------------------------
// Module-scope scratch. 84M floats = 336 MB, lifetime-aliased.
// Map (float offsets):
//   [       0,15360000) nh_hi  (bf16 [80000][384]: ch0-127 radar->enhanced, 128-383 image)
//   [15360000,30720000) nh_lo  (read by comb-proj; conv+gate read HI only)
//   [30720000,51200000) seq_comb fp32 [80000][256] -> hbuf (bf16 [80000][512]) after out-proj
//   [51200000,61440000) score/idx -> qh -> xbuf (fp32 80000x128)
//   [61440000,71680000) kvh fp32 [40000][256] -> gatepre fp32 [80000][128] (after attn)
//   [71680000,81920000) G: hscore fp32 [80000][128] -> kvn/qn/o/xn split-bf16 -> delta fp32
//   [81920000,82313216) WSEG: split weights (786432 u16 = 393216 floats)
//   [82330000,83657104) conv wgt hi/lo (2x1327104 u16)
//   [83900000,83900128) bias_pad (128 f, padded score_b1)
//   [83900160,83900224) zero page (64 f = 256 B of zeros, for masked DMA rows)
// d_out written ONLY by conv + bn_relu. d_ws unused. d_in never written.
// R4 lesson: simultaneous same-line misses from different XCDs don't merge —
// keep B-sharing tiles temporally separated (p-major gemm grid, hw-major conv).
// R6 lesson: conv loop order LOCKED to shift-outer/icb-inner (562us measured).
// R8: staging via global_load_lds (linear LDS dest + inverse-swizzled global
// src — rule #21 both-sides-or-neither; masked rows read a global zero page).
// ---------------------------------------------------------------------------
__device__ float g_arena[84000000];
__device__ float g_stats[768];

// ---------------------------------------------------------------------------
// helpers
// ---------------------------------------------------------------------------
__device__ __forceinline__ float wave_sum(float v) {
#pragma unroll
    for (int o = 32; o > 0; o >>= 1) v += __shfl_down(v, o, 64);
    return v;
}

// async global->LDS 16B DMA. Per-lane global src; LDS dest must be linear
// (wave-uniform base + lane*16). Drained by __syncthreads (vmcnt in barrier).
__device__ __forceinline__ void gload16(const u16* g, u16* l) {
    __builtin_amdgcn_global_load_lds(
        (const __attribute__((address_space(1))) u32*)(g),
        (__attribute__((address_space(3))) u32*)(l),
        16, 0, 0);
}

// split fp32 -> bf16 hi + bf16 lo (lo = bf16(x - fp32(hi))); residual ~2^-17 rel
__device__ __forceinline__ void bf_split(float v, u16& h, u16& l) {
    __hip_bfloat16 bh = __float2bfloat16(v);
    float hv = __bfloat162float(bh);
    __hip_bfloat16 bl = __float2bfloat16(v - hv);
    h = *reinterpret_cast<u16*>(&bh);
    l = *reinterpret_cast<u16*>(&bl);
}

__device__ __forceinline__ void store_split4(u16* ph, u16* pl, float4 v) {
    u16 h0, l0, h1, l1, h2, l2, h3, l3;
    bf_split(v.x, h0, l0); bf_split(v.y, h1, l1);
    bf_split(v.z, h2, l2); bf_split(v.w, h3, l3);
    *(ushort4*)ph = make_ushort4(h0, h1, h2, h3);
    *(ushort4*)pl = make_ushort4(l0, l1, l2, l3);
}

// ---------------------------------------------------------------------------
// split_weights: all gemm weights -> WSEG split bf16 (hi|lo per segment).
//   inproj   0      49152  | outproj 98304 16384 | ffn1 131072 65536
//   ffn2     262144 65536  | delta  393216 16384 | gate 425984 49152
//   comb     524288 98304  (zero-padded [256][384])
//   score1   720896 32768  (zero-padded [128][256], rows 64-127 = 0)
// plus bias_pad[128] and zero page[64]. 393472 threads -> grid 1537 x 256.
// ---------------------------------------------------------------------------
__global__ __launch_bounds__(256) void split_weights_kernel(
    const float* __restrict__ w_inproj, const float* __restrict__ w_outproj,
    const float* __restrict__ w_ffn1, const float* __restrict__ w_ffn2,
    const float* __restrict__ w_delta, const float* __restrict__ w_gate,
    const float* __restrict__ w_img, const float* __restrict__ w_rad,
    const float* __restrict__ w_sc1, const float* __restrict__ b_sc1,
    u16* __restrict__ wseg, float* __restrict__ bias_pad,
    float* __restrict__ zpage)
{
    int i = blockIdx.x * 256 + threadIdx.x;
    if (i >= 393408) return;
    if (i >= 393344) {                       // zero page (64 floats)
        zpage[i - 393344] = 0.f;
        return;
    }
    if (i >= 393216) {                       // bias_pad
        int l = i - 393216;
        bias_pad[l] = (l < 64) ? b_sc1[l] : 0.f;
        return;
    }
    float v; int base, numel, local;
    if (i < 49152)       { local = i;          base = 0;      numel = 49152; v = w_inproj[local]; }
    else if (i < 65536)  { local = i - 49152;  base = 98304;  numel = 16384; v = w_outproj[local]; }
    else if (i < 131072) { local = i - 65536;  base = 131072; numel = 65536; v = w_ffn1[local]; }
    else if (i < 196608) { local = i - 131072; base = 262144; numel = 65536; v = w_ffn2[local]; }
    else if (i < 212992) { local = i - 196608; base = 393216; numel = 16384; v = w_delta[local]; }
    else if (i < 262144) { local = i - 212992; base = 425984; numel = 49152; v = w_gate[local]; }
    else if (i < 360448) {
        local = i - 262144; base = 524288; numel = 98304;
        int oc = local / 384, c = local - oc * 384;
        if (oc < 128) v = (c < 128) ? w_rad[oc * 128 + c] : 0.f;
        else          v = (c >= 128) ? w_img[(oc - 128) * 256 + (c - 128)] : 0.f;
    } else {
        local = i - 360448; base = 720896; numel = 32768;
        int oc = local / 256, c = local - oc * 256;
        v = (oc < 64) ? w_sc1[oc * 256 + c] : 0.f;
    }
    u16 hh, ll;
    bf_split(v, hh, ll);
    wseg[base + local] = hh;
    wseg[base + numel + local] = ll;
}

// ---------------------------------------------------------------------------
// mfma_gemm: out[p][ocb+oc] = sum_k B[p][k] * W[ocb+oc][k]  (+bias,+resid,relu)
// Grid: (ceil(P/128), Nout/128) — p-tiles FASTEST (R4 lesson).
// BMODE: 0 = split bf16 planes; 1 = single bf16 (no sBl -> 48 KB LDS, 3 blk/CU);
//        2 = fp32 split-on-the-fly (B reg-staged; A still DMA)
// OMODE: 0 = fp32 out; 1 = bf16 out.  resid has row stride rstride.
// R8: A/B bf16 staging via global_load_lds — linear LDS dest, global src chunk
// swz = cl^(row&7) (same involution as the read-side XOR). OOB rows -> zpage.
// ---------------------------------------------------------------------------
template <int BMODE, int OMODE, bool RELU>
__global__ __launch_bounds__(256, (BMODE == 1) ? 3 : 2) void mfma_gemm_kernel(
    const u16* __restrict__ Ah, const u16* __restrict__ Al,
    const u16* __restrict__ bh, const u16* __restrict__ bl,
    const float* __restrict__ bf, int bstride,
    const float* __restrict__ bias, const float* __restrict__ resid, int rstride,
    float* __restrict__ outf, u16* __restrict__ outh,
    int K, int Nout, int P, const u16* __restrict__ zp)
{
    __shared__ alignas(16) u16 sAh[8192], sAl[8192], sBh[8192];
    __shared__ alignas(16) u16 sBl[(BMODE != 1) ? 8192 : 8];

    const int tid  = threadIdx.x;
    const int lane = tid & 63;
    const int wid  = tid >> 6;
    const int wrm  = wid >> 1;
    const int wcn  = wid & 1;
    const int p0   = blockIdx.x * 128;
    const int ocb  = blockIdx.y * 128;

    const int r0  = tid >> 3;
    const int cl  = tid & 7;
    const int swz = cl ^ (r0 & 7);

    f32x4 acc[4][4];
#pragma unroll
    for (int i = 0; i < 4; ++i)
#pragma unroll
        for (int j = 0; j < 4; ++j) acc[i][j] = (f32x4){0.f, 0.f, 0.f, 0.f};

    const int fr = lane & 15;
    const int fc = lane >> 4;

    for (int kk = 0; kk < K; kk += 64) {
        __syncthreads();
#pragma unroll
        for (int k = 0; k < 4; ++k) {
            int row = r0 + k * 32;
            int dlin = row * 64 + cl * 8;                 // LINEAR dest (u16)
            size_t ga = (size_t)(ocb + row) * K + kk + swz * 8;  // swizzled src
            gload16(&Ah[ga], &sAh[dlin]);
            gload16(&Al[ga], &sAl[dlin]);
            int p = p0 + row;
            if (BMODE == 0) {
                size_t gb = (size_t)p * bstride + kk + swz * 8;
                const u16* bsh = (p < P) ? &bh[gb] : zp;
                const u16* bsl = (p < P) ? &bl[gb] : zp;
                gload16(bsh, &sBh[dlin]);
                gload16(bsl, &sBl[dlin]);
            } else if (BMODE == 1) {
                size_t gb = (size_t)p * bstride + kk + swz * 8;
                const u16* bsh = (p < P) ? &bh[gb] : zp;
                gload16(bsh, &sBh[dlin]);
            } else {
                int di = row * 64 + swz * 8;              // swizzled LDS write
                short8v vh8 = {0,0,0,0,0,0,0,0}, vl8 = {0,0,0,0,0,0,0,0};
                if (p < P) {
                    const float* src = bf + (size_t)p * bstride + kk + cl * 8;
                    float4 f0 = *(const float4*)(src);
                    float4 f1 = *(const float4*)(src + 4);
                    float fv[8] = {f0.x, f0.y, f0.z, f0.w, f1.x, f1.y, f1.z, f1.w};
#pragma unroll
                    for (int j = 0; j < 8; ++j) {
                        u16 hh, ll;
                        bf_split(fv[j], hh, ll);
                        vh8[j] = (short)hh;
                        vl8[j] = (short)ll;
                    }
                }
                *(short8v*)&sBh[di] = vh8;
                *(short8v*)&sBl[di] = vl8;
            }
        }
        __syncthreads();
#pragma unroll
        for (int h = 0; h < 2; ++h) {
            const int kc = h * 4 + fc;
            short8v bhf[4], blf[4];
#pragma unroll
            for (int nn = 0; nn < 4; ++nn) {
                int row = wcn * 64 + nn * 16 + fr;
                int idx = row * 64 + ((kc ^ (row & 7)) << 3);
                bhf[nn] = *(const short8v*)&sBh[idx];
                if (BMODE != 1) blf[nn] = *(const short8v*)&sBl[idx];
            }
#pragma unroll
            for (int mm = 0; mm < 4; ++mm) {
                int row = wrm * 64 + mm * 16 + fr;
                int idx = row * 64 + ((kc ^ (row & 7)) << 3);
                short8v ahf = *(const short8v*)&sAh[idx];
                short8v alf = *(const short8v*)&sAl[idx];
#pragma unroll
                for (int nn = 0; nn < 4; ++nn)
                    acc[mm][nn] = __builtin_amdgcn_mfma_f32_16x16x32_bf16(
                        ahf, bhf[nn], acc[mm][nn], 0, 0, 0);
                if (BMODE != 1) {
#pragma unroll
                    for (int nn = 0; nn < 4; ++nn)
                        acc[mm][nn] = __builtin_amdgcn_mfma_f32_16x16x32_bf16(
                            ahf, blf[nn], acc[mm][nn], 0, 0, 0);
                }
#pragma unroll
                for (int nn = 0; nn < 4; ++nn)
                    acc[mm][nn] = __builtin_amdgcn_mfma_f32_16x16x32_bf16(
                        alf, bhf[nn], acc[mm][nn], 0, 0, 0);
            }
        }
    }

    // epilogue: D[row=oc][col=pos] -> out[p][oc], 4 regs = 4 consecutive oc
#pragma unroll
    for (int mm = 0; mm < 4; ++mm) {
        int base = ocb + wrm * 64 + mm * 16 + fc * 4;
        float4 bv = {0.f, 0.f, 0.f, 0.f};
        if (bias) bv = *(const float4*)&bias[base];
#pragma unroll
        for (int nn = 0; nn < 4; ++nn) {
            int p = p0 + wcn * 64 + nn * 16 + fr;
            if (p < P) {
                size_t row = (size_t)p * Nout + base;
                float4 r;
                r.x = acc[mm][nn][0] + bv.x;
                r.y = acc[mm][nn][1] + bv.y;
                r.z = acc[mm][nn][2] + bv.z;
                r.w = acc[mm][nn][3] + bv.w;
                if (resid) {
                    float4 rr = *(const float4*)&resid[(size_t)p * rstride + base - ocb];
                    r.x += rr.x; r.y += rr.y; r.z += rr.z; r.w += rr.w;
                }
                if (RELU) {
                    r.x = fmaxf(r.x, 0.f); r.y = fmaxf(r.y, 0.f);
                    r.z = fmaxf(r.z, 0.f); r.w = fmaxf(r.w, 0.f);
                }
                if (OMODE == 0) {
                    *(float4*)&outf[row] = r;
                } else {
                    __hip_bfloat16 b0 = __float2bfloat16(r.x);
                    __hip_bfloat16 b1 = __float2bfloat16(r.y);
                    __hip_bfloat16 b2 = __float2bfloat16(r.z);
                    __hip_bfloat16 b3 = __float2bfloat16(r.w);
                    *(ushort4*)&outh[row] = make_ushort4(
                        *reinterpret_cast<u16*>(&b0), *reinterpret_cast<u16*>(&b1),
                        *reinterpret_cast<u16*>(&b2), *reinterpret_cast<u16*>(&b3));
                }
            }
        }
    }
}

// ---------------------------------------------------------------------------
// score_reduce: score[p] = h[p][0:64] . w2 + b2  (h from MFMA score-gemm)
// ---------------------------------------------------------------------------
__global__ __launch_bounds__(256) void score_reduce_kernel(
    const float* __restrict__ h, const float* __restrict__ w2,
    const float* __restrict__ b2, float* __restrict__ score)
{
    int p = blockIdx.x * 4 + (threadIdx.x >> 6);
    int l = threadIdx.x & 63;
    float v = h[(size_t)p * 128 + l] * w2[l];
    v = wave_sum(v);
    if (l == 0) score[p] = v + b2[0];
}

// ---------------------------------------------------------------------------
// topk: exact stable rank selection (matches jax.lax.top_k tie-breaking)
// ---------------------------------------------------------------------------
__global__ __launch_bounds__(256) void topk_kernel(
    const float* __restrict__ score, int* __restrict__ idx)
{
    __shared__ float s[200];
    const int n = blockIdx.x;
    const int t = threadIdx.x;
    if (t < 200) s[t] = score[(size_t)n * 200 + t];
    __syncthreads();
    if (t < 200) {
        float my = s[t];
        int cnt = 0;
        for (int j = 0; j < 200; j++) {
            float o = s[j];
            cnt += (o > my) || (o == my && j < t);
        }
        if (cnt < 100) idx[n * 100 + cnt] = t;
    }
}

// ---------------------------------------------------------------------------
// ln_gather: out[r][:] = LN(in[src_row][:]) * g + b  -> split bf16 planes
// ---------------------------------------------------------------------------
__global__ __launch_bounds__(256) void ln_gather_kernel(
    const float* __restrict__ in, int stride, const int* __restrict__ gidx,
    const float* __restrict__ g, const float* __restrict__ bb,
    u16* __restrict__ oh, u16* __restrict__ ol)
{
    __shared__ float red[4];
    const int tid = threadIdx.x;
    const int grp = tid >> 7;
    const int t = tid & 127;
    const int r = blockIdx.x * 2 + grp;

    size_t src_row;
    if (gidx) src_row = (size_t)(r / 100) * 200 + gidx[r];
    else      src_row = (size_t)r;

    float x = in[src_row * stride + t];
    float s = wave_sum(x);
    if ((tid & 63) == 0) red[tid >> 6] = s;
    __syncthreads();
    float m = (red[grp * 2] + red[grp * 2 + 1]) * 0.0078125f;
    float d = x - m;
    float s2 = wave_sum(d * d);
    __syncthreads();
    if ((tid & 63) == 0) red[tid >> 6] = s2;
    __syncthreads();
    float var = (red[grp * 2] + red[grp * 2 + 1]) * 0.0078125f;
    float y = d * rsqrtf(var + EPSF) * g[t] + bb[t];
    u16 hh, ll;
    bf_split(y, hh, ll);
    oh[(size_t)r * 128 + t] = hh;
    ol[(size_t)r * 128 + t] = ll;
}

// ---------------------------------------------------------------------------
// attention: block = (head h, row n); thread = one query w (<200)
// K/V interleaved in kvh [40000][256]; outputs split bf16 planes
// ---------------------------------------------------------------------------
__global__ __launch_bounds__(256) void attention_kernel(
    const float* __restrict__ qh, const float* __restrict__ kvh,
    u16* __restrict__ o_hi, u16* __restrict__ o_lo)
{
    __shared__ float sk[100][16];
    __shared__ float sv[100][16];
    const int h = blockIdx.x;
    const int n = blockIdx.y;
    const int tid = threadIdx.x;

    for (int e = tid; e < 1600; e += 256) {
        int kk = e >> 4, d = e & 15;
        size_t src = ((size_t)n * 100 + kk) * 256 + h * 16 + d;
        sk[kk][d] = kvh[src];
        sv[kk][d] = kvh[src + 128];
    }
    __syncthreads();

    if (tid < 200) {
        const float* qp = &qh[((size_t)n * 200 + tid) * 128 + h * 16];
        float4 q0 = *(const float4*)(qp + 0);
        float4 q1 = *(const float4*)(qp + 4);
        float4 q2 = *(const float4*)(qp + 8);
        float4 q3 = *(const float4*)(qp + 12);

        float m = -INFINITY, l = 0.f;
        float4 a0 = {0,0,0,0}, a1 = {0,0,0,0}, a2 = {0,0,0,0}, a3 = {0,0,0,0};

        for (int kk = 0; kk < 100; kk++) {
            const float4* kp = (const float4*)&sk[kk][0];
            float s = q0.x*kp[0].x + q0.y*kp[0].y + q0.z*kp[0].z + q0.w*kp[0].w
                    + q1.x*kp[1].x + q1.y*kp[1].y + q1.z*kp[1].z + q1.w*kp[1].w
                    + q2.x*kp[2].x + q2.y*kp[2].y + q2.z*kp[2].z + q2.w*kp[2].w
                    + q3.x*kp[3].x + q3.y*kp[3].y + q3.z*kp[3].z + q3.w*kp[3].w;
            s *= 0.25f;
            float nm = fmaxf(m, s);
            float corr = __expf(m - nm);
            float pe = __expf(s - nm);
            l = l * corr + pe;
            const float4* vp = (const float4*)&sv[kk][0];
            float4 v0 = vp[0], v1 = vp[1], v2 = vp[2], v3 = vp[3];
            a0.x = a0.x * corr + pe * v0.x; a0.y = a0.y * corr + pe * v0.y;
            a0.z = a0.z * corr + pe * v0.z; a0.w = a0.w * corr + pe * v0.w;
            a1.x = a1.x * corr + pe * v1.x; a1.y = a1.y * corr + pe * v1.y;
            a1.z = a1.z * corr + pe * v1.z; a1.w = a1.w * corr + pe * v1.w;
            a2.x = a2.x * corr + pe * v2.x; a2.y = a2.y * corr + pe * v2.y;
            a2.z = a2.z * corr + pe * v2.z; a2.w = a2.w * corr + pe * v2.w;
            a3.x = a3.x * corr + pe * v3.x; a3.y = a3.y * corr + pe * v3.y;
            a3.z = a3.z * corr + pe * v3.z; a3.w = a3.w * corr + pe * v3.w;
            m = nm;
        }
        float inv = 1.f / l;
        a0.x *= inv; a0.y *= inv; a0.z *= inv; a0.w *= inv;
        a1.x *= inv; a1.y *= inv; a1.z *= inv; a1.w *= inv;
        a2.x *= inv; a2.y *= inv; a2.z *= inv; a2.w *= inv;
        a3.x *= inv; a3.y *= inv; a3.z *= inv; a3.w *= inv;
        size_t ob = ((size_t)n * 200 + tid) * 128 + h * 16;
        store_split4(&o_hi[ob + 0],  &o_lo[ob + 0],  a0);
        store_split4(&o_hi[ob + 4],  &o_lo[ob + 4],  a1);
        store_split4(&o_hi[ob + 8],  &o_lo[ob + 8],  a2);
        store_split4(&o_hi[ob + 12], &o_lo[ob + 12], a3);
    }
}

// ---------------------------------------------------------------------------
// prep_weights: fuse_w [oc][ic][ky][kx] fp32 -> conv wgt hi/lo [oc][s][ic] bf16
// ---------------------------------------------------------------------------
__global__ __launch_bounds__(256) void prep_weights_kernel(
    const float* __restrict__ fw, u16* __restrict__ wh, u16* __restrict__ wl)
{
    int idx = blockIdx.x * 256 + threadIdx.x;   // < 384*384 = 147456
    int oc = idx / 384;
    int ic = idx - oc * 384;
    const float* src = fw + (size_t)idx * 9;
    u16* dh = wh + (size_t)oc * 3456 + ic;
    u16* dl = wl + (size_t)oc * 3456 + ic;
#pragma unroll
    for (int s = 0; s < 9; ++s) {
        u16 hh, ll;
        bf_split(src[s], hh, ll);
        dh[(size_t)s * 384] = hh;
        dl[(size_t)s * 384] = ll;
    }
}

// ---------------------------------------------------------------------------
// convert_nhwc: concat(radar[0:128], image[0:256]) NCHW fp32 -> NHWC bf16 split
// ---------------------------------------------------------------------------
__global__ __launch_bounds__(256) void convert_nhwc_kernel(
    const float* __restrict__ radar, const float* __restrict__ image,
    u16* __restrict__ oh, u16* __restrict__ ol)
{
    int p = blockIdx.x * 256 + threadIdx.x;
    if (p >= 80000) return;
    int cg = blockIdx.y;               // 0..5 -> channels [cg*64, cg*64+64)
    int b = p >= 40000 ? 1 : 0;
    int hw = p - b * 40000;
    u16* ph = oh + (size_t)p * 384 + cg * 64;
    u16* pl = ol + (size_t)p * 384 + cg * 64;
#pragma unroll 1
    for (int g = 0; g < 8; ++g) {
        short8v vh, vl;
#pragma unroll
        for (int j = 0; j < 8; ++j) {
            int c = cg * 64 + g * 8 + j;
            float v = (c < 128)
                ? radar[((size_t)(b * 128 + c)) * 40000 + hw]
                : image[((size_t)(b * 256 + (c - 128))) * 40000 + hw];
            u16 hh, ll;
            bf_split(v, hh, ll);
            vh[j] = (short)hh;
            vl[j] = (short)ll;
        }
        *(short8v*)&ph[g * 8] = vh;
        *(short8v*)&pl[g * 8] = vl;
    }
}

// ---------------------------------------------------------------------------
// enhance_fuse: nh[p][0:128] = bf16(radar + gamma*sigmoid(gatepre)*rmask*delta)
// HI plane only — nh_lo radar chunk is dead (conv + gate read hi only).
// ---------------------------------------------------------------------------
__global__ __launch_bounds__(256) void enhance_fuse_kernel(
    const float* __restrict__ delta, const float* __restrict__ gatepre,
    const float* __restrict__ radar, const float* __restrict__ gamma_p,
    u16* __restrict__ nh)
{
    __shared__ float srad[64][136];   // [pos][oc], padded
    const int tid = threadIdx.x;
    const int blk = blockIdx.x;        // 0..1249 (625 per b)
    const int b = blk >= 625 ? 1 : 0;
    const int hw0 = (blk - b * 625) * 64;
    const int p0 = b * 40000 + hw0;

#pragma unroll
    for (int i = 0; i < 32; ++i) {
        int e = tid + i * 256;         // 8192 elems
        int oc = e >> 6, pos = e & 63;
        srad[pos][oc] = radar[((size_t)(b * 128 + oc)) * 40000 + hw0 + pos];
    }
    __syncthreads();

    const float gmm = gamma_p[0];
    const int c4 = tid & 31;           // oc quad index
    const int rr = tid >> 5;           // 0..7
#pragma unroll
    for (int j = 0; j < 8; ++j) {
        int pos = j * 8 + rr;
        int p = p0 + pos;
        int hw = hw0 + pos;
        int hrow = hw / 200;
        float rm = fmaxf(0.3f, 1.0f - 0.7f * ((float)hrow * (1.0f / 199.0f)));
        float4 dv = *(const float4*)&delta[(size_t)p * 128 + c4 * 4];
        float4 gv = *(const float4*)&gatepre[(size_t)p * 128 + c4 * 4];
        float4 rv = *(const float4*)&srad[pos][c4 * 4];
        float rx = rv.x + gmm * (1.f / (1.f + __expf(-gv.x))) * rm * dv.x;
        float ry = rv.y + gmm * (1.f / (1.f + __expf(-gv.y))) * rm * dv.y;
        float rz = rv.z + gmm * (1.f / (1.f + __expf(-gv.z))) * rm * dv.z;
        float rw = rv.w + gmm * (1.f / (1.f + __expf(-gv.w))) * rm * dv.w;
        __hip_bfloat16 b0 = __float2bfloat16(rx);
        __hip_bfloat16 b1 = __float2bfloat16(ry);
        __hip_bfloat16 b2 = __float2bfloat16(rz);
        __hip_bfloat16 b3 = __float2bfloat16(rw);
        *(ushort4*)&nh[(size_t)p * 384 + c4 * 4] = make_ushort4(
            *reinterpret_cast<u16*>(&b0), *reinterpret_cast<u16*>(&b1),
            *reinterpret_cast<u16*>(&b2), *reinterpret_cast<u16*>(&b3));
    }
}

// ---------------------------------------------------------------------------
// conv_mfma: 3x3 SAME conv as 9 shifted GEMMs on matrix cores.
// R5-EXACT loop order (shift OUTER, icb INNER — R6 lesson: locked).
// Input = HI bf16 plane only (2 MFMA products). LDS 48 KB -> 3 blocks/CU.
// Grid (313,2,3) hw-major (R4 lesson).
// R8: A/B staging via global_load_lds (linear LDS dest + swizzled global src);
// masked border rows DMA from the global zero page.
// ---------------------------------------------------------------------------
__global__ __launch_bounds__(256, 3) void conv_mfma_kernel(
    const u16* __restrict__ nhwc_hi,
    const u16* __restrict__ wgt_hi,  const u16* __restrict__ wgt_lo,
    float* __restrict__ out, const u16* __restrict__ zp)
{
    __shared__ alignas(16) u16 sAh[8192], sAl[8192], sBh[8192];  // 48 KB

    const int tid  = threadIdx.x;
    const int lane = tid & 63;
    const int wid  = tid >> 6;
    const int wrm  = wid >> 1;
    const int wcn  = wid & 1;
    const int hw0  = blockIdx.x * 128;
    const int b    = blockIdx.y;
    const int oc0  = blockIdx.z * 128;

    const int r0  = tid >> 3;
    const int cl  = tid & 7;
    const int swz = cl ^ (r0 & 7);

    const int y0 = hw0 / 200;
    const int x0 = hw0 - y0 * 200;

    f32x4 acc[4][4];
#pragma unroll
    for (int i = 0; i < 4; ++i)
#pragma unroll
        for (int j = 0; j < 4; ++j) acc[i][j] = (f32x4){0.f, 0.f, 0.f, 0.f};

    size_t abase[4];
#pragma unroll
    for (int k = 0; k < 4; ++k)
        abase[k] = (size_t)(oc0 + r0 + k * 32) * 3456 + swz * 8;   // swizzled src

    const int fr = lane & 15;
    const int fc = lane >> 4;

    for (int s = 0; s < 9; ++s) {
        const int dy = s / 3 - 1;
        const int dx = s % 3 - 1;
        size_t bsrc[4];
        int bval[4];
#pragma unroll
        for (int k = 0; k < 4; ++k) {
            int row = r0 + k * 32;
            int hwo = hw0 + row;
            int xr  = x0 + row;
            int wrp = (xr >= 200) ? 1 : 0;
            int yy  = y0 + wrp + dy;
            int xx  = xr - wrp * 200 + dx;
            int v = (hwo < 40000) && ((unsigned)yy < 200u) && ((unsigned)xx < 200u);
            bval[k] = v;
            bsrc[k] = v ? ((size_t)(b * 40000 + yy * 200 + xx) * 384 + swz * 8) : 0;
        }
        const size_t wofs = (size_t)s * 384;

        for (int icb = 0; icb < 6; ++icb) {
            const int ic0 = icb * 64;
            __syncthreads();
#pragma unroll
            for (int k = 0; k < 4; ++k) {
                int dlin = (r0 + k * 32) * 64 + cl * 8;   // LINEAR dest
                size_t ga = abase[k] + wofs + ic0;
                gload16(&wgt_hi[ga], &sAh[dlin]);
                gload16(&wgt_lo[ga], &sAl[dlin]);
                const u16* bs = bval[k] ? &nhwc_hi[bsrc[k] + ic0] : zp;
                gload16(bs, &sBh[dlin]);
            }
            __syncthreads();
#pragma unroll
            for (int h = 0; h < 2; ++h) {
                const int kc = h * 4 + fc;
                short8v bhf[4];
#pragma unroll
                for (int nn = 0; nn < 4; ++nn) {
                    int row = wcn * 64 + nn * 16 + fr;
                    int idx = row * 64 + ((kc ^ (row & 7)) << 3);
                    bhf[nn] = *(const short8v*)&sBh[idx];
                }
#pragma unroll
                for (int mm = 0; mm < 4; ++mm) {
                    int row = wrm * 64 + mm * 16 + fr;
                    int idx = row * 64 + ((kc ^ (row & 7)) << 3);
                    short8v ahf = *(const short8v*)&sAh[idx];
                    short8v alf = *(const short8v*)&sAl[idx];
#pragma unroll
                    for (int nn = 0; nn < 4; ++nn)
                        acc[mm][nn] = __builtin_amdgcn_mfma_f32_16x16x32_bf16(
                            ahf, bhf[nn], acc[mm][nn], 0, 0, 0);
#pragma unroll
                    for (int nn = 0; nn < 4; ++nn)
                        acc[mm][nn] = __builtin_amdgcn_mfma_f32_16x16x32_bf16(
                            alf, bhf[nn], acc[mm][nn], 0, 0, 0);
                }
            }
        }
    }

#pragma unroll
    for (int mm = 0; mm < 4; ++mm) {
        int oc = oc0 + wrm * 64 + mm * 16 + fc * 4;
#pragma unroll
        for (int nn = 0; nn < 4; ++nn) {
            int p = hw0 + wcn * 64 + nn * 16 + fr;
            if (p < 40000) {
                float* op = out + (size_t)(b * 384 + oc) * 40000 + p;
#pragma unroll
                for (int r = 0; r < 4; ++r)
                    op[(size_t)r * 40000] = acc[mm][nn][r];
            }
        }
    }
}

// ---------------------------------------------------------------------------
// zero_stats + conv_stats (4 hw-chunks per channel, atomic accumulate)
// ---------------------------------------------------------------------------
__global__ void zero_stats_kernel() {
    int i = blockIdx.x * 256 + threadIdx.x;
    if (i < 768) g_stats[i] = 0.f;
}

__global__ __launch_bounds__(256) void conv_stats_kernel(const float* __restrict__ out)
{
    const int c = blockIdx.x;           // 0..383
    const int chunk = blockIdx.y;       // 0..3
    float s1 = 0.f, s2 = 0.f;
#pragma unroll
    for (int b = 0; b < 2; ++b) {
        const float4* pp = (const float4*)(out + (size_t)(b * 384 + c) * 40000)
                         + (size_t)chunk * 2500;
        for (int i = threadIdx.x; i < 2500; i += 256) {
            float4 v = pp[i];
            s1 += v.x + v.y + v.z + v.w;
            s2 += v.x * v.x + v.y * v.y + v.z * v.z + v.w * v.w;
        }
    }
    s1 = wave_sum(s1);
    s2 = wave_sum(s2);
    __shared__ float r1[4], r2[4];
    if ((threadIdx.x & 63) == 0) {
        r1[threadIdx.x >> 6] = s1;
        r2[threadIdx.x >> 6] = s2;
    }
    __syncthreads();
    if (threadIdx.x == 0) {
        atomicAdd(&g_stats[c * 2],     r1[0] + r1[1] + r1[2] + r1[3]);
        atomicAdd(&g_stats[c * 2 + 1], r2[0] + r2[1] + r2[2] + r2[3]);
    }
}

// ---------------------------------------------------------------------------
// bn_relu: in-place on d_out
// ---------------------------------------------------------------------------
__global__ __launch_bounds__(256) void bn_relu_kernel(
    float* __restrict__ out, const float* __restrict__ g,
    const float* __restrict__ bb)
{
    int i = blockIdx.x * 256 + threadIdx.x;   // float4 index < 7,680,000
    int flat = i * 4;
    int oc = (flat / 40000) % 384;
    float m = g_stats[oc * 2] * (1.f / 80000.f);
    float v = g_stats[oc * 2 + 1] * (1.f / 80000.f) - m * m;
    float inv = rsqrtf(v + EPSF);
    float sc = g[oc] * inv;
    float sh = bb[oc] - m * sc;
    float4 c = ((float4*)out)[i];
    c.x = fmaxf(c.x * sc + sh, 0.f);
    c.y = fmaxf(c.y * sc + sh, 0.f);
    c.z = fmaxf(c.z * sc + sh, 0.f);
    c.w = fmaxf(c.w * sc + sh, 0.f);
    ((float4*)out)[i] = c;
}

// ---------------------------------------------------------------------------
// launch
// ---------------------------------------------------------------------------
extern "C" void kernel_launch(void* const* d_in, const int* in_sizes, int n_in,
                              void* d_out, int out_size, void* d_ws, size_t ws_size,
                              hipStream_t stream)
{
    (void)in_sizes; (void)n_in; (void)out_size; (void)d_ws; (void)ws_size;

    const float* radar      = (const float*)d_in[0];
    const float* image      = (const float*)d_in[1];
    const float* img_proj_w = (const float*)d_in[2];
    const float* rad_proj_w = (const float*)d_in[3];
    const float* in_proj_w  = (const float*)d_in[4];
    const float* in_proj_b  = (const float*)d_in[5];
    const float* out_proj_w = (const float*)d_in[6];
    const float* out_proj_b = (const float*)d_in[7];
    const float* ln1q_g     = (const float*)d_in[8];
    const float* ln1q_b     = (const float*)d_in[9];
    const float* ln1kv_g    = (const float*)d_in[10];
    const float* ln1kv_b    = (const float*)d_in[11];
    const float* ln2_g      = (const float*)d_in[12];
    const float* ln2_b      = (const float*)d_in[13];
    const float* ffn_w1     = (const float*)d_in[14];
    const float* ffn_b1     = (const float*)d_in[15];
    const float* ffn_w2     = (const float*)d_in[16];
    const float* ffn_b2     = (const float*)d_in[17];
    const float* score_w1   = (const float*)d_in[18];
    const float* score_b1   = (const float*)d_in[19];
    const float* score_w2   = (const float*)d_in[20];
    const float* score_b2   = (const float*)d_in[21];
    const float* rad_delta_w= (const float*)d_in[22];
    const float* gamma      = (const float*)d_in[23];
    const float* gate_w     = (const float*)d_in[24];
    const float* gate_b     = (const float*)d_in[25];
    const float* fuse_w     = (const float*)d_in[26];
    const float* bn_g       = (const float*)d_in[27];
    const float* bn_b       = (const float*)d_in[28];

    float* arena = nullptr;
    hipGetSymbolAddress((void**)&arena, HIP_SYMBOL(g_arena));

    // --- arena regions (see map above) ---
    u16*   nh_hi    = (u16*)arena;                      // [80000][384] hi
    u16*   nh_lo    = (u16*)(arena + 15360000);         // [80000][384] lo
    float* seq_comb = arena + 30720000;                 // [80000][256] fp32
    float* score    = arena + 51200000;                 // 80000 f
    int*   idx      = (int*)(arena + 51280000);         // 40000 int
    float* qh       = arena + 51200000;                 // overlays score/idx
    float* xbuf     = arena + 51200000;                 // overlays qh
    float* kvh      = arena + 61440000;                 // [40000][256] fp32
    float* gatepre  = arena + 61440000;                 // [80000][128] over kvh (after attn)
    float* hscore   = arena + 71680000;                 // [80000][128] fp32 (score MLP hidden)
    u16*   gbase    = (u16*)(arena + 71680000);         // split-plane region G (over dead hscore)
    u16*   kvn_hi   = gbase,            *kvn_lo = gbase + 5120000;   // [40000][128]
    u16*   qn_hi    = gbase,            *qn_lo  = gbase + 10240000;  // [80000][128]
    u16*   o_hi     = gbase,            *o_lo   = gbase + 10240000;  // [80000][128]
    u16*   xn_hi    = gbase,            *xn_lo  = gbase + 10240000;  // [80000][128]
    float* delta    = arena + 71680000;                 // [80000][128] over G
    u16*   hbuf     = (u16*)(arena + 30720000);         // [80000][512] bf16 over seq_comb
    u16*   wseg     = (u16*)(arena + 81920000);         // 786432 u16 -> ends 82313216 f
    u16*   cwgt_hi  = (u16*)(arena + 82330000);         // conv wgt
    u16*   cwgt_lo  = cwgt_hi + 1327104;                // ends 83657104 f
    float* bias_pad = arena + 83900000;                 // 128 f (padded score_b1)
    float* zpage_f  = arena + 83900160;                 // 64 f zero page (16B-aligned)
    const u16* zp   = (const u16*)zpage_f;

    // split-weight sub-pointers (u16 offsets within wseg)
    const u16* w_q_hi    = wseg + 0,      *w_q_lo    = wseg + 49152;          // in_proj rows 0-127
    const u16* w_kv_hi   = wseg + 16384,  *w_kv_lo   = wseg + 49152 + 16384;  // rows 128-383 (256)
    const u16* w_out_hi  = wseg + 98304,  *w_out_lo  = wseg + 114688;
    const u16* w_ffn1_hi = wseg + 131072, *w_ffn1_lo = wseg + 196608;
    const u16* w_ffn2_hi = wseg + 262144, *w_ffn2_lo = wseg + 327680;
    const u16* w_dlt_hi  = wseg + 393216, *w_dlt_lo  = wseg + 409600;
    const u16* w_gate_hi = wseg + 425984, *w_gate_lo = wseg + 475136;
    const u16* w_comb_hi = wseg + 524288, *w_comb_lo = wseg + 622592;         // [256][384] padded
    const u16* w_sc1_hi  = wseg + 720896, *w_sc1_lo  = wseg + 753664;         // [128][256] padded

    const dim3 blk(256);

    // prep: weight splits + zero page + NHWC conversion of (radar|image)
    split_weights_kernel<<<dim3(1537), blk, 0, stream>>>(
        in_proj_w, out_proj_w, ffn_w1, ffn_w2, rad_delta_w, gate_w,
        img_proj_w, rad_proj_w, score_w1, score_b1, wseg, bias_pad, zpage_f);
    prep_weights_kernel<<<dim3(576), blk, 0, stream>>>(fuse_w, cwgt_hi, cwgt_lo);
    convert_nhwc_kernel<<<dim3(313, 6), blk, 0, stream>>>(radar, image, nh_hi, nh_lo);

    // combined projection: seq_comb[p][0:128]=rad, [128:256]=img
    mfma_gemm_kernel<0, 0, false><<<dim3(625, 2), blk, 0, stream>>>(
        w_comb_hi, w_comb_lo, nh_hi, nh_lo, nullptr, 384,
        nullptr, nullptr, 0, seq_comb, nullptr, 384, 256, 80000, zp);

    // scoring MLP (MFMA, padded W1/bias) -> hscore; reduce with w2; top-k
    mfma_gemm_kernel<2, 0, true><<<dim3(625, 1), blk, 0, stream>>>(
        w_sc1_hi, w_sc1_lo, nullptr, nullptr, seq_comb, 256,
        bias_pad, nullptr, 0, hscore, nullptr, 256, 128, 80000, zp);
    score_reduce_kernel<<<dim3(20000), blk, 0, stream>>>(
        hscore, score_w2, score_b2, score);
    topk_kernel<<<dim3(400), blk, 0, stream>>>(score, idx);

    // gathered LN(kv) -> kvn planes (over dead hscore); merged K+V projection
    ln_gather_kernel<<<dim3(20000), blk, 0, stream>>>(
        seq_comb + 128, 256, idx, ln1kv_g, ln1kv_b, kvn_hi, kvn_lo);
    mfma_gemm_kernel<0, 0, false><<<dim3(313, 2), blk, 0, stream>>>(
        w_kv_hi, w_kv_lo, kvn_hi, kvn_lo, nullptr, 128,
        in_proj_b + 128, nullptr, 0, kvh, nullptr, 128, 256, 40000, zp);

    // LN(q) -> qn planes (over dead kvn), Q projection -> qh (over dead score/idx)
    ln_gather_kernel<<<dim3(40000), blk, 0, stream>>>(
        seq_comb, 256, nullptr, ln1q_g, ln1q_b, qn_hi, qn_lo);
    mfma_gemm_kernel<0, 0, false><<<dim3(625, 1), blk, 0, stream>>>(
        w_q_hi, w_q_lo, qn_hi, qn_lo, nullptr, 128,
        in_proj_b, nullptr, 0, qh, nullptr, 128, 128, 80000, zp);

    // attention -> o planes (over dead qn)
    attention_kernel<<<dim3(8, 400), blk, 0, stream>>>(qh, kvh, o_hi, o_lo);

    // out-proj + residual (rad part of seq_comb, rstride 256) -> xbuf
    mfma_gemm_kernel<0, 0, false><<<dim3(625, 1), blk, 0, stream>>>(
        w_out_hi, w_out_lo, o_hi, o_lo, nullptr, 128,
        out_proj_b, seq_comb, 256, xbuf, nullptr, 128, 128, 80000, zp);

    // FFN: ln2 -> xn planes (over dead o); FFN1 -> hbuf bf16 (over dead seq_comb);
    // FFN2 -> xbuf in place
    ln_gather_kernel<<<dim3(40000), blk, 0, stream>>>(
        xbuf, 128, nullptr, ln2_g, ln2_b, xn_hi, xn_lo);
    mfma_gemm_kernel<0, 1, true><<<dim3(625, 4), blk, 0, stream>>>(
        w_ffn1_hi, w_ffn1_lo, xn_hi, xn_lo, nullptr, 128,
        ffn_b1, nullptr, 0, nullptr, hbuf, 128, 512, 80000, zp);
    mfma_gemm_kernel<1, 0, false><<<dim3(625, 1), blk, 0, stream>>>(
        w_ffn2_hi, w_ffn2_lo, hbuf, nullptr, nullptr, 512,
        ffn_b2, xbuf, 128, xbuf, nullptr, 512, 128, 80000, zp);

    // enhance: delta gemm (fp32 B, over dead xn) + gate gemm (hi-only B, over
    // dead kvh) + fused sigmoid/rmask/residual writing nh radar channels
    mfma_gemm_kernel<2, 0, false><<<dim3(625, 1), blk, 0, stream>>>(
        w_dlt_hi, w_dlt_lo, nullptr, nullptr, xbuf, 128,
        nullptr, nullptr, 0, delta, nullptr, 128, 128, 80000, zp);
    mfma_gemm_kernel<1, 0, false><<<dim3(625, 1), blk, 0, stream>>>(
        w_gate_hi, w_gate_lo, nh_hi, nullptr, nullptr, 384,
        gate_b, nullptr, 0, gatepre, nullptr, 384, 128, 80000, zp);
    enhance_fuse_kernel<<<dim3(1250), blk, 0, stream>>>(
        delta, gatepre, radar, gamma, nh_hi);

    // conv 3x3 (MFMA, R5-exact loop order, DMA staging) -> d_out; stats; bn
    conv_mfma_kernel<<<dim3(313, 2, 3), blk, 0, stream>>>(
        nh_hi, cwgt_hi, cwgt_lo, (float*)d_out, zp);
    zero_stats_kernel<<<dim3(3), blk, 0, stream>>>();
    conv_stats_kernel<<<dim3(384, 4), blk, 0, stream>>>((const float*)d_out);
    bn_relu_kernel<<<dim3(30000), blk, 0, stream>>>(
        (float*)d_out, bn_g, bn_b);
}